// Round 2
// baseline (1371.201 us; speedup 1.0000x reference)
//
#include <hip/hip_runtime.h>

#define NN 100000
#define NE 1600000
#define NG 512
#define FIN 64
#define HD 128
#define NSTEP 6
#define SCHUNK 1024
#define NBLK 98    // ceil(NN/SCHUNK)

// ---- bucketed CSR fill geometry ----
#define BROWS 128               // dst nodes per bucket
#define NBUCK 782               // ceil(NN/BROWS)
#define EPER 16                 // edges per thread in k_bin
#define BINBLK 391              // ceil(NE / (256*EPER))

typedef _Float16 f16x8 __attribute__((ext_vector_type(8)));
typedef _Float16 f16x4 __attribute__((ext_vector_type(4)));
typedef float    f32x4 __attribute__((ext_vector_type(4)));

__device__ __forceinline__ float sigm(float x) { return 1.f / (1.f + __expf(-x)); }
__device__ __forceinline__ float tanhfast(float x) { return 2.f / (1.f + __expf(-2.f * x)) - 1.f; }

// LDS tile index with XOR swizzle (128-col tiles, 16B chunks)
__device__ __forceinline__ int lidx(int r, int col) {
    return r * 128 + ((((col >> 3) ^ (r & 15)) << 3) | (col & 7));
}

// ---------------- CSR build ----------------
__global__ void k_count(const int* __restrict__ dst, int* __restrict__ counts) {
    int e = blockIdx.x * 256 + threadIdx.x;
    if (e < NE) atomicAdd(&counts[dst[e]], 1);
}

__global__ void k_scan1(const int* __restrict__ counts, int* __restrict__ indptr, int* __restrict__ aux) {
    __shared__ int sh[256];
    int blk = blockIdx.x, tid = threadIdx.x;
    int base = blk * SCHUNK + tid * 4;
    int v0 = 0, v1 = 0, v2 = 0, v3 = 0;
    if (base + 0 < NN) v0 = counts[base + 0];
    if (base + 1 < NN) v1 = counts[base + 1];
    if (base + 2 < NN) v2 = counts[base + 2];
    if (base + 3 < NN) v3 = counts[base + 3];
    int tsum = v0 + v1 + v2 + v3;
    sh[tid] = tsum;
    __syncthreads();
    for (int off = 1; off < 256; off <<= 1) {
        int t = (tid >= off) ? sh[tid - off] : 0;
        __syncthreads();
        sh[tid] += t;
        __syncthreads();
    }
    int excl = sh[tid] - tsum;
    if (base + 0 < NN) indptr[base + 0] = excl;
    if (base + 1 < NN) indptr[base + 1] = excl + v0;
    if (base + 2 < NN) indptr[base + 2] = excl + v0 + v1;
    if (base + 3 < NN) indptr[base + 3] = excl + v0 + v1 + v2;
    if (tid == 255) aux[blk] = sh[255];
}

__global__ void k_scan2(int* __restrict__ aux) {
    __shared__ int sh[128];
    int tid = threadIdx.x;
    int v = (tid < NBLK) ? aux[tid] : 0;
    sh[tid] = v;
    __syncthreads();
    for (int off = 1; off < 128; off <<= 1) {
        int t = (tid >= off) ? sh[tid - off] : 0;
        __syncthreads();
        sh[tid] += t;
        __syncthreads();
    }
    if (tid < NBLK) aux[tid] = sh[tid] - v;
}

__global__ void k_scan3(int* __restrict__ indptr, const int* __restrict__ aux) {
    int blk = blockIdx.x, tid = threadIdx.x;
    int off = aux[blk];
    int base = blk * SCHUNK + tid * 4;
#pragma unroll
    for (int i = 0; i < 4; ++i) {
        int idx = base + i;
        if (idx < NN) indptr[idx] += off;
    }
    if (blk == 0 && tid == 0) indptr[NN] = NE;
}

// [R7 post-mortem: bucketed 2-pass with per-EDGE global atomics on 782 counters was
//  3x WORSE - atomic serialization. This scheme reserves per-BLOCK (LDS histogram +
//  <=782 global atomics/block) and phase-2 writes each bucket's csr window densely.
//  Measured: replaced 126us/105MB-write k_fill with ~25us total. KEEP.]

// bucket cursors <- indptr at bucket boundaries
__global__ void k_bcinit(const int* __restrict__ indptr, int* __restrict__ bcur) {
    int b = blockIdx.x * 256 + threadIdx.x;
    if (b < NBUCK) bcur[b] = indptr[b * BROWS];
}

// phase 1: bin (src,dst) pairs into per-bucket append regions
__global__ void __launch_bounds__(256) k_bin(const int* __restrict__ src, const int* __restrict__ dst,
                                             int* __restrict__ bcur, int2* __restrict__ pairs) {
    __shared__ int hist[NBUCK];
    __shared__ int base[NBUCK];
    int tid = threadIdx.x;
    for (int i = tid; i < NBUCK; i += 256) hist[i] = 0;
    __syncthreads();
    int e0 = blockIdx.x * (256 * EPER) + tid;
    int s[EPER], d[EPER], rk[EPER];
#pragma unroll
    for (int k = 0; k < EPER; ++k) {
        int e = e0 + k * 256;
        if (e < NE) {
            s[k] = src[e];
            d[k] = dst[e];
            rk[k] = atomicAdd(&hist[d[k] >> 7], 1);   // LDS atomic: local rank within (block,bucket)
        }
    }
    __syncthreads();
    for (int i = tid; i < NBUCK; i += 256) {
        int c = hist[i];
        base[i] = c ? atomicAdd(&bcur[i], c) : 0;     // one global atomic per (block,bucket)
    }
    __syncthreads();
#pragma unroll
    for (int k = 0; k < EPER; ++k) {
        int e = e0 + k * 256;
        if (e < NE) pairs[base[d[k] >> 7] + rk[k]] = make_int2(s[k], d[k]);
    }
}

// phase 2: one block per bucket; dense contiguous csr window per bucket
__global__ void __launch_bounds__(256) k_fill2(const int2* __restrict__ pairs,
                                               const int* __restrict__ indptr, int* __restrict__ csr) {
    __shared__ int cnt[BROWS];
    __shared__ int ip[BROWS];
    int b = blockIdx.x, tid = threadIdx.x;
    int n0 = b * BROWS;
    if (tid < BROWS) {
        cnt[tid] = 0;
        ip[tid] = (n0 + tid < NN) ? indptr[n0 + tid] : NE;
    }
    __syncthreads();
    int s = indptr[n0];
    int nend = n0 + BROWS; if (nend > NN) nend = NN;
    int e = indptr[nend];
    for (int i = s + tid; i < e; i += 256) {
        int2 p = pairs[i];
        int li = p.y & (BROWS - 1);                    // p.y - n0 (n0 is a multiple of 128)
        int r = atomicAdd(&cnt[li], 1);
        csr[ip[li] + r] = p.x;
    }
}

// ---------------- B prep (GRU weights), swizzled to MFMA fragment order ----------------
// Logical Bcat[c][k]: c=0..511 (g=c>>7: 0=r,1=z,2=i_n,3=h_n; j=c&127), k=0..255.
//   k<128:  g!=3 ? Weff[s][k][jj] : 0    (Weff = Wmp[s] @ Wih^T)
//   k>=128: g!=2 ? Whh[jj][k-128] : 0
__global__ void k_prepB(const float* __restrict__ Wmp, const float* __restrict__ Wih,
                        const float* __restrict__ Whh, _Float16* __restrict__ Bsw) {
    __shared__ float wih[HD];
    int b = blockIdx.x;          // s*512 + c
    int s = b >> 9;
    int c = b & 511;
    int g = c >> 7;
    int j = c & 127;
    int jj = (g < 2) ? c : (j + 256);
    int k = threadIdx.x;         // 0..255
    if (k < HD) wih[k] = Wih[(size_t)jj * HD + k];
    __syncthreads();
    float val = 0.f;
    if (k < 128) {
        if (g != 3) {
            const float* wm = Wmp + ((size_t)s * HD + k) * HD;
            float acc = 0.f;
#pragma unroll 8
            for (int t = 0; t < HD; ++t) acc += wm[t] * wih[t];
            val = acc;
        }
    } else {
        if (g != 2) val = Whh[(size_t)jj * HD + (k - 128)];
    }
    int l16 = c & 15, sub = (c >> 4) & 1, w = (c >> 5) & 3;
    int t = g * 2 + sub;
    int p = k >> 5, quad = (k >> 3) & 3, je = k & 7;
    size_t idx = (size_t)s * 131072 + ((size_t)((w * 8 + t) * 8 + p) * 64 + quad * 16 + l16) * 8 + je;
    Bsw[idx] = (_Float16)val;
}

// ---------------- W_in prep: fragment-order hi/lo fp16 ----------------
__global__ void k_prepWin(const float* __restrict__ Win,
                          _Float16* __restrict__ BihW, _Float16* __restrict__ BilW) {
    int gid = blockIdx.x * 256 + threadIdx.x;   // 0..8191
    int jj = gid & 7;
    int lane = (gid >> 3) & 63;
    int p = (gid >> 9) & 1;
    int t = (gid >> 10) & 7;
    int k = p * 32 + (lane >> 4) * 8 + jj;
    int col = t * 16 + (lane & 15);
    float val = Win[(size_t)k * HD + col];
    _Float16 hi = (_Float16)val;
    BihW[gid] = hi;
    BilW[gid] = (_Float16)(val - (float)hi);
}

// ---------------- input layer (MFMA): h = tanh(x @ W_in), fp16 out ----------------
__global__ void __launch_bounds__(256) k_input(const float* __restrict__ x,
                                               const _Float16* __restrict__ BihW,
                                               const _Float16* __restrict__ BilW,
                                               _Float16* __restrict__ H) {
    __shared__ _Float16 Xh[64 * 64];
    __shared__ _Float16 Xl[64 * 64];
    __shared__ _Float16 Oh[64 * 128];
    int tid = threadIdx.x;
    int w = tid >> 6, lane = tid & 63;
    int quad = lane >> 4, l16 = lane & 15;
    int m0 = blockIdx.x * 64;

#pragma unroll
    for (int it = 0; it < 4; ++it) {
        int c = it * 256 + tid;          // 1024 chunks of 4 floats
        int row = c >> 4, cc = c & 15;
        int grow = m0 + row; if (grow >= NN) grow = NN - 1;
        float4 v = ((const float4*)(x + (size_t)grow * FIN))[cc];
        f16x4 vh, vl;
        vh[0] = (_Float16)v.x; vl[0] = (_Float16)(v.x - (float)vh[0]);
        vh[1] = (_Float16)v.y; vl[1] = (_Float16)(v.y - (float)vh[1]);
        vh[2] = (_Float16)v.z; vl[2] = (_Float16)(v.z - (float)vh[2]);
        vh[3] = (_Float16)v.w; vl[3] = (_Float16)(v.w - (float)vh[3]);
        int ld = row * 64 + ((((cc >> 1) ^ (row & 7)) << 3)) + (cc & 1) * 4;
        *(f16x4*)(&Xh[ld]) = vh;
        *(f16x4*)(&Xl[ld]) = vl;
    }
    __syncthreads();

    f32x4 acc[4][2];
#pragma unroll
    for (int mi = 0; mi < 4; ++mi) { acc[mi][0] = (f32x4){0,0,0,0}; acc[mi][1] = (f32x4){0,0,0,0}; }

#pragma unroll
    for (int p = 0; p < 2; ++p) {
        int ch = p * 4 + quad;
        f16x8 ah[4], al[4];
#pragma unroll
        for (int mi = 0; mi < 4; ++mi) {
            int r = mi * 16 + l16;
            int li = r * 64 + ((ch ^ (r & 7)) << 3);
            ah[mi] = *(const f16x8*)(&Xh[li]);
            al[mi] = *(const f16x8*)(&Xl[li]);
        }
#pragma unroll
        for (int t2 = 0; t2 < 2; ++t2) {
            int t = w * 2 + t2;
            f16x8 bh = *(const f16x8*)(BihW + ((size_t)(t * 2 + p) * 64 + lane) * 8);
            f16x8 blv = *(const f16x8*)(BilW + ((size_t)(t * 2 + p) * 64 + lane) * 8);
#pragma unroll
            for (int mi = 0; mi < 4; ++mi) {
                acc[mi][t2] = __builtin_amdgcn_mfma_f32_16x16x32_f16(ah[mi], bh, acc[mi][t2], 0, 0, 0);
                acc[mi][t2] = __builtin_amdgcn_mfma_f32_16x16x32_f16(ah[mi], blv, acc[mi][t2], 0, 0, 0);
                acc[mi][t2] = __builtin_amdgcn_mfma_f32_16x16x32_f16(al[mi], bh, acc[mi][t2], 0, 0, 0);
            }
        }
    }

#pragma unroll
    for (int t2 = 0; t2 < 2; ++t2) {
        int j = (w * 2 + t2) * 16 + l16;
#pragma unroll
        for (int mi = 0; mi < 4; ++mi) {
#pragma unroll
            for (int reg = 0; reg < 4; ++reg) {
                int row = mi * 16 + quad * 4 + reg;
                Oh[lidx(row, j)] = (_Float16)tanhfast(acc[mi][t2][reg]);
            }
        }
    }
    __syncthreads();
#pragma unroll
    for (int it = 0; it < 4; ++it) {
        int c = it * 256 + tid;
        int row = c >> 4, kc = c & 15;
        int grow = m0 + row;
        if (grow < NN) {
            int ld = row * 128 + ((kc ^ (row & 15)) << 3);
            *(f16x8*)(H + (size_t)grow * HD + kc * 8) = *(const f16x8*)(&Oh[ld]);
        }
    }
}

// ---------------- fused step: agg (gather->LDS) + MFMA GEMM + GRU (ping-pong H) ----------------
// [R1: separate k_agg (~80us, latency-bound gather, MFMA idle) + k_ggemm (81us,
//  MfmaUtil 9.4%, VALUBusy 28%, HBM 24% -- nothing saturated) serialized at the
//  kernel boundary, plus a 51MB/step Shi round-trip. Fused: gather writes Sl LDS
//  directly; resident blocks overlap gather-phase with MFMA-phase. H ping-pong
//  (Hin->Hout) keeps gather sources stable.]
__global__ void __launch_bounds__(256, 3) k_step(
        const _Float16* __restrict__ Hin, _Float16* __restrict__ Hout,
        const int* __restrict__ indptr, const int* __restrict__ csr,
        const _Float16* __restrict__ Bsw,
        const float* __restrict__ bih, const float* __restrict__ bhh) {
    __shared__ _Float16 Sl[64 * 128];
    __shared__ _Float16 Hh[64 * 128];
    int tid = threadIdx.x;
    int w = tid >> 6, lane = tid & 63;
    int quad = lane >> 4, l16 = lane & 15;
    int m0 = blockIdx.x * 64;

    // stage own 64 rows of Hin -> Hh (A-frags for H-phases + GRU hold)
#pragma unroll
    for (int it = 0; it < 4; ++it) {
        int c = it * 256 + tid;
        int row = c >> 4, kc = c & 15;
        int grow = m0 + row; if (grow >= NN) grow = NN - 1;
        int ld = row * 128 + ((kc ^ (row & 15)) << 3);
        *(f16x8*)(&Hh[ld]) = *(const f16x8*)(Hin + (size_t)grow * HD + kc * 8);
    }

    // gather: Sl[row] = sum_{in-edges} Hin[src]; wave w owns rows w*16..w*16+15
    {
        int slot = lane >> 4;
        int cg = lane & 15;
        const _Float16* hp = Hin + cg * 8;
        for (int nv = 0; nv < 16; ++nv) {
            int row = w * 16 + nv;
            int v = m0 + row;
            int s = 0, e = 0;
            if (v < NN) { s = indptr[v]; e = indptr[v + 1]; }
            float a0 = 0.f, a1 = 0.f, a2 = 0.f, a3 = 0.f, a4 = 0.f, a5 = 0.f, a6 = 0.f, a7 = 0.f;
            int i = s + slot;
            for (; i + 12 < e; i += 16) {
                int u0 = csr[i], u1 = csr[i + 4], u2 = csr[i + 8], u3 = csr[i + 12];
                f16x8 t0 = *(const f16x8*)(hp + (size_t)u0 * HD);
                f16x8 t1 = *(const f16x8*)(hp + (size_t)u1 * HD);
                f16x8 t2 = *(const f16x8*)(hp + (size_t)u2 * HD);
                f16x8 t3 = *(const f16x8*)(hp + (size_t)u3 * HD);
                a0 += (float)t0[0] + (float)t1[0] + (float)t2[0] + (float)t3[0];
                a1 += (float)t0[1] + (float)t1[1] + (float)t2[1] + (float)t3[1];
                a2 += (float)t0[2] + (float)t1[2] + (float)t2[2] + (float)t3[2];
                a3 += (float)t0[3] + (float)t1[3] + (float)t2[3] + (float)t3[3];
                a4 += (float)t0[4] + (float)t1[4] + (float)t2[4] + (float)t3[4];
                a5 += (float)t0[5] + (float)t1[5] + (float)t2[5] + (float)t3[5];
                a6 += (float)t0[6] + (float)t1[6] + (float)t2[6] + (float)t3[6];
                a7 += (float)t0[7] + (float)t1[7] + (float)t2[7] + (float)t3[7];
            }
            for (; i < e; i += 4) {
                int u0 = csr[i];
                f16x8 t0 = *(const f16x8*)(hp + (size_t)u0 * HD);
                a0 += (float)t0[0]; a1 += (float)t0[1]; a2 += (float)t0[2]; a3 += (float)t0[3];
                a4 += (float)t0[4]; a5 += (float)t0[5]; a6 += (float)t0[6]; a7 += (float)t0[7];
            }
            a0 += __shfl_down(a0, 32); a1 += __shfl_down(a1, 32);
            a2 += __shfl_down(a2, 32); a3 += __shfl_down(a3, 32);
            a4 += __shfl_down(a4, 32); a5 += __shfl_down(a5, 32);
            a6 += __shfl_down(a6, 32); a7 += __shfl_down(a7, 32);
            a0 += __shfl_down(a0, 16); a1 += __shfl_down(a1, 16);
            a2 += __shfl_down(a2, 16); a3 += __shfl_down(a3, 16);
            a4 += __shfl_down(a4, 16); a5 += __shfl_down(a5, 16);
            a6 += __shfl_down(a6, 16); a7 += __shfl_down(a7, 16);
            if (lane < 16) {
                f16x8 o;
                o[0] = (_Float16)a0; o[1] = (_Float16)a1; o[2] = (_Float16)a2; o[3] = (_Float16)a3;
                o[4] = (_Float16)a4; o[5] = (_Float16)a5; o[6] = (_Float16)a6; o[7] = (_Float16)a7;
                *(f16x8*)(&Sl[row * 128 + ((cg ^ (row & 15)) << 3)]) = o;
            }
        }
    }
    __syncthreads();

    f32x4 acc[4][8];
#pragma unroll
    for (int mi = 0; mi < 4; ++mi)
#pragma unroll
        for (int t = 0; t < 8; ++t) acc[mi][t] = (f32x4){0.f, 0.f, 0.f, 0.f};

    const _Float16* bw = Bsw + (size_t)(w * 8) * 8 * 512 + lane * 8;

    // S phases (gates r,z,i_n -> t=0..5)
#pragma unroll
    for (int p = 0; p < 4; ++p) {
        f16x8 a[4];
#pragma unroll
        for (int mi = 0; mi < 4; ++mi)
            a[mi] = *(const f16x8*)(&Sl[lidx(mi * 16 + l16, p * 32 + quad * 8)]);
#pragma unroll
        for (int t = 0; t < 6; ++t) {
            f16x8 b = *(const f16x8*)(bw + (size_t)(t * 8 + p) * 512);
#pragma unroll
            for (int mi = 0; mi < 4; ++mi)
                acc[mi][t] = __builtin_amdgcn_mfma_f32_16x16x32_f16(a[mi], b, acc[mi][t], 0, 0, 0);
        }
    }

    // H phases (gates r,z,h_n -> t={0,1,2,3,6,7})
#pragma unroll
    for (int p = 0; p < 4; ++p) {
        f16x8 a[4];
#pragma unroll
        for (int mi = 0; mi < 4; ++mi)
            a[mi] = *(const f16x8*)(&Hh[lidx(mi * 16 + l16, p * 32 + quad * 8)]);
#pragma unroll
        for (int tt = 0; tt < 6; ++tt) {
            int t = (tt < 4) ? tt : (tt + 2);
            f16x8 b = *(const f16x8*)(bw + (size_t)(t * 8 + p + 4) * 512);
#pragma unroll
            for (int mi = 0; mi < 4; ++mi)
                acc[mi][t] = __builtin_amdgcn_mfma_f32_16x16x32_f16(a[mi], b, acc[mi][t], 0, 0, 0);
        }
    }

    __syncthreads();   // all H-LDS A-reads done before epilogue overwrites Hh

    // epilogue: gates; in-place RMW on Hh (each li touched by exactly one thread)
#pragma unroll
    for (int ns = 0; ns < 2; ++ns) {
        int j = w * 32 + ns * 16 + l16;
        float br  = bih[j]       + bhh[j];
        float bz  = bih[j + 128] + bhh[j + 128];
        float bin = bih[j + 256];
        float bhn = bhh[j + 256];
#pragma unroll
        for (int mi = 0; mi < 4; ++mi) {
#pragma unroll
            for (int reg = 0; reg < 4; ++reg) {
                int row = mi * 16 + quad * 4 + reg;
                int li = lidx(row, j);
                float hold = (float)Hh[li];
                float r = sigm(acc[mi][0 + ns][reg] + br);
                float z = sigm(acc[mi][2 + ns][reg] + bz);
                float n = tanhfast(acc[mi][4 + ns][reg] + bin + r * (acc[mi][6 + ns][reg] + bhn));
                Hh[li] = (_Float16)((1.f - z) * n + z * hold);
            }
        }
    }
    __syncthreads();

#pragma unroll
    for (int it = 0; it < 4; ++it) {
        int c = it * 256 + tid;
        int row = c >> 4, kc = c & 15;
        int grow = m0 + row;
        if (grow < NN) {
            int ld = row * 128 + ((kc ^ (row & 15)) << 3);
            *(f16x8*)(Hout + (size_t)grow * HD + kc * 8) = *(const f16x8*)(&Hh[ld]);
        }
    }
}

// ---------------- pooling + head ----------------
__global__ void k_ginit(int* __restrict__ gs, int* __restrict__ ge) {
    int g = threadIdx.x;
    if (g < NG) { gs[g] = 0; ge[g] = 0; }
}

__global__ void k_bounds(const int* __restrict__ batch, int* __restrict__ gs, int* __restrict__ ge) {
    int i = blockIdx.x * 256 + threadIdx.x;
    if (i >= NN) return;
    int b = batch[i];
    if (i == 0 || batch[i - 1] != b) gs[b] = i;
    if (i == NN - 1 || batch[i + 1] != b) ge[b] = i + 1;
}

__global__ void k_pool(const _Float16* __restrict__ H,
                       const int* __restrict__ gs, const int* __restrict__ ge,
                       const float* __restrict__ Wp, const float* __restrict__ bp,
                       float* __restrict__ out) {
    __shared__ float red[HD];
    int g = blockIdx.x, tid = threadIdx.x;
    int s = gs[g], e = ge[g];
    float acc = 0.f;
    for (int n = s; n < e; ++n) acc += (float)H[(size_t)n * HD + tid];
    int cnt = e - s;
    float pooled = acc / (float)(cnt > 0 ? cnt : 1);
    red[tid] = fmaxf(pooled, 0.f) * Wp[tid];
    __syncthreads();
    for (int off = 64; off > 0; off >>= 1) {
        if (tid < off) red[tid] += red[tid + off];
        __syncthreads();
    }
    if (tid == 0) out[g] = red[0] + bp[0];
}

extern "C" void kernel_launch(void* const* d_in, const int* in_sizes, int n_in,
                              void* d_out, int out_size, void* d_ws, size_t ws_size,
                              hipStream_t stream) {
    const float* x   = (const float*)d_in[0];
    const int*   ei  = (const int*)d_in[1];
    const int*   bat = (const int*)d_in[2];
    const float* Win = (const float*)d_in[3];
    const float* Wmp = (const float*)d_in[4];
    const float* Wih = (const float*)d_in[5];
    const float* Whh = (const float*)d_in[6];
    const float* bih = (const float*)d_in[7];
    const float* bhh = (const float*)d_in[8];
    const float* Wp  = (const float*)d_in[9];
    const float* bp  = (const float*)d_in[10];
    float* out = (float*)d_out;

    const int* esrc = ei;
    const int* edst = ei + NE;

    char* w = (char*)d_ws;
    _Float16* H   = (_Float16*)w; w += (size_t)NN * HD * 2;
    _Float16* H2  = (_Float16*)w; w += (size_t)NN * HD * 2;   // ping-pong partner
    _Float16* Bsw = (_Float16*)w; w += (size_t)NSTEP * 131072 * 2;
    _Float16* BihW = (_Float16*)w; w += 8192 * 2;
    _Float16* BilW = (_Float16*)w; w += 8192 * 2;
    int* indptr  = (int*)w;   w += 400128;
    int* cursor  = (int*)w;   w += 400128;   // counts during scan; bucket cursors after
    int* csr     = (int*)w;   w += (size_t)NE * 4;
    int* aux     = (int*)w;   w += 512;
    int* gs      = (int*)w;   w += NG * 4;
    int* ge      = (int*)w;   w += NG * 4;

    // pairs buffer aliases H2 (12.8MB; consumed by k_fill2 before H2's first write)
    int2* pairs = (int2*)H2;
    int*  bcur  = cursor;    // counts no longer needed after scan3

    // CSR build: count -> scan -> bucket-bin -> dense per-bucket fill
    hipMemsetAsync(cursor, 0, (size_t)NN * 4, stream);
    k_count<<<NE / 256, 256, 0, stream>>>(edst, cursor);
    k_scan1<<<NBLK, 256, 0, stream>>>(cursor, indptr, aux);
    k_scan2<<<1, 128, 0, stream>>>(aux);
    k_scan3<<<NBLK, 256, 0, stream>>>(indptr, aux);
    k_bcinit<<<(NBUCK + 255) / 256, 256, 0, stream>>>(indptr, bcur);
    k_bin<<<BINBLK, 256, 0, stream>>>(esrc, edst, bcur, pairs);
    k_fill2<<<NBUCK, 256, 0, stream>>>(pairs, indptr, csr);

    // weight prep + input layer
    k_prepB<<<NSTEP * 512, 256, 0, stream>>>(Wmp, Wih, Whh, Bsw);
    k_prepWin<<<32, 256, 0, stream>>>(Win, BihW, BilW);
    k_input<<<(NN + 63) / 64, 256, 0, stream>>>(x, BihW, BilW, H);

    // 6 fused message-passing + GEMM/GRU steps, ping-pong H<->H2 (even count -> ends in H)
    _Float16* Ha = H;
    _Float16* Hb = H2;
    for (int st = 0; st < NSTEP; ++st) {
        k_step<<<(NN + 63) / 64, 256, 0, stream>>>(Ha, Hb, indptr, csr,
                                                   Bsw + (size_t)st * 131072,
                                                   bih, bhh);
        _Float16* t = Ha; Ha = Hb; Hb = t;
    }

    // pooling + head
    k_ginit<<<1, NG, 0, stream>>>(gs, ge);
    k_bounds<<<(NN + 255) / 256, 256, 0, stream>>>(bat, gs, ge);
    k_pool<<<NG, HD, 0, stream>>>(H, gs, ge, Wp, bp, out);
}

// Round 3
// 928.231 us; speedup vs baseline: 1.4772x; 1.4772x over previous
//
#include <hip/hip_runtime.h>

#define NN 100000
#define NE 1600000
#define NG 512
#define FIN 64
#define HD 128
#define NSTEP 6
#define SCHUNK 1024
#define NBLK 98    // ceil(NN/SCHUNK)

// ---- bucketed CSR fill geometry ----
#define BROWS 128               // dst nodes per bucket
#define NBUCK 782               // ceil(NN/BROWS)
#define EPER 16                 // edges per thread in k_bin
#define BINBLK 391              // ceil(NE / (256*EPER))

typedef _Float16 f16x8 __attribute__((ext_vector_type(8)));
typedef _Float16 f16x4 __attribute__((ext_vector_type(4)));
typedef float    f32x4 __attribute__((ext_vector_type(4)));

__device__ __forceinline__ float sigm(float x) { return 1.f / (1.f + __expf(-x)); }
__device__ __forceinline__ float tanhfast(float x) { return 2.f / (1.f + __expf(-2.f * x)) - 1.f; }

// LDS tile index with XOR swizzle (128-col tiles, 16B chunks)
__device__ __forceinline__ int lidx(int r, int col) {
    return r * 128 + ((((col >> 3) ^ (r & 15)) << 3) | (col & 7));
}

// ---------------- CSR build ----------------
__global__ void k_count(const int* __restrict__ dst, int* __restrict__ counts) {
    int e = blockIdx.x * 256 + threadIdx.x;
    if (e < NE) atomicAdd(&counts[dst[e]], 1);
}

__global__ void k_scan1(const int* __restrict__ counts, int* __restrict__ indptr, int* __restrict__ aux) {
    __shared__ int sh[256];
    int blk = blockIdx.x, tid = threadIdx.x;
    int base = blk * SCHUNK + tid * 4;
    int v0 = 0, v1 = 0, v2 = 0, v3 = 0;
    if (base + 0 < NN) v0 = counts[base + 0];
    if (base + 1 < NN) v1 = counts[base + 1];
    if (base + 2 < NN) v2 = counts[base + 2];
    if (base + 3 < NN) v3 = counts[base + 3];
    int tsum = v0 + v1 + v2 + v3;
    sh[tid] = tsum;
    __syncthreads();
    for (int off = 1; off < 256; off <<= 1) {
        int t = (tid >= off) ? sh[tid - off] : 0;
        __syncthreads();
        sh[tid] += t;
        __syncthreads();
    }
    int excl = sh[tid] - tsum;
    if (base + 0 < NN) indptr[base + 0] = excl;
    if (base + 1 < NN) indptr[base + 1] = excl + v0;
    if (base + 2 < NN) indptr[base + 2] = excl + v0 + v1;
    if (base + 3 < NN) indptr[base + 3] = excl + v0 + v1 + v2;
    if (tid == 255) aux[blk] = sh[255];
}

__global__ void k_scan2(int* __restrict__ aux) {
    __shared__ int sh[128];
    int tid = threadIdx.x;
    int v = (tid < NBLK) ? aux[tid] : 0;
    sh[tid] = v;
    __syncthreads();
    for (int off = 1; off < 128; off <<= 1) {
        int t = (tid >= off) ? sh[tid - off] : 0;
        __syncthreads();
        sh[tid] += t;
        __syncthreads();
    }
    if (tid < NBLK) aux[tid] = sh[tid] - v;
}

__global__ void k_scan3(int* __restrict__ indptr, const int* __restrict__ aux) {
    int blk = blockIdx.x, tid = threadIdx.x;
    int off = aux[blk];
    int base = blk * SCHUNK + tid * 4;
#pragma unroll
    for (int i = 0; i < 4; ++i) {
        int idx = base + i;
        if (idx < NN) indptr[idx] += off;
    }
    if (blk == 0 && tid == 0) indptr[NN] = NE;
}

// [R0: direct-scatter fill = 105MB write-amp, 126us. R1: this bucketed scheme
//  (per-BLOCK reservation, dense per-bucket windows) = ~25us total. KEEP.]

// bucket cursors <- indptr at bucket boundaries
__global__ void k_bcinit(const int* __restrict__ indptr, int* __restrict__ bcur) {
    int b = blockIdx.x * 256 + threadIdx.x;
    if (b < NBUCK) bcur[b] = indptr[b * BROWS];
}

// phase 1: bin (src,dst) pairs into per-bucket append regions
__global__ void __launch_bounds__(256) k_bin(const int* __restrict__ src, const int* __restrict__ dst,
                                             int* __restrict__ bcur, int2* __restrict__ pairs) {
    __shared__ int hist[NBUCK];
    __shared__ int base[NBUCK];
    int tid = threadIdx.x;
    for (int i = tid; i < NBUCK; i += 256) hist[i] = 0;
    __syncthreads();
    int e0 = blockIdx.x * (256 * EPER) + tid;
    int s[EPER], d[EPER], rk[EPER];
#pragma unroll
    for (int k = 0; k < EPER; ++k) {
        int e = e0 + k * 256;
        if (e < NE) {
            s[k] = src[e];
            d[k] = dst[e];
            rk[k] = atomicAdd(&hist[d[k] >> 7], 1);   // LDS atomic: local rank within (block,bucket)
        }
    }
    __syncthreads();
    for (int i = tid; i < NBUCK; i += 256) {
        int c = hist[i];
        base[i] = c ? atomicAdd(&bcur[i], c) : 0;     // one global atomic per (block,bucket)
    }
    __syncthreads();
#pragma unroll
    for (int k = 0; k < EPER; ++k) {
        int e = e0 + k * 256;
        if (e < NE) pairs[base[d[k] >> 7] + rk[k]] = make_int2(s[k], d[k]);
    }
}

// phase 2: one block per bucket; dense contiguous csr window per bucket
__global__ void __launch_bounds__(256) k_fill2(const int2* __restrict__ pairs,
                                               const int* __restrict__ indptr, int* __restrict__ csr) {
    __shared__ int cnt[BROWS];
    __shared__ int ip[BROWS];
    int b = blockIdx.x, tid = threadIdx.x;
    int n0 = b * BROWS;
    if (tid < BROWS) {
        cnt[tid] = 0;
        ip[tid] = (n0 + tid < NN) ? indptr[n0 + tid] : NE;
    }
    __syncthreads();
    int s = indptr[n0];
    int nend = n0 + BROWS; if (nend > NN) nend = NN;
    int e = indptr[nend];
    for (int i = s + tid; i < e; i += 256) {
        int2 p = pairs[i];
        int li = p.y & (BROWS - 1);                    // p.y - n0 (n0 is a multiple of 128)
        int r = atomicAdd(&cnt[li], 1);
        csr[ip[li] + r] = p.x;
    }
}

// ---------------- B prep (GRU weights), swizzled to MFMA fragment order ----------------
// Logical Bcat[c][k]: c=0..511 (g=c>>7: 0=r,1=z,2=i_n,3=h_n; j=c&127), k=0..255.
//   k<128:  g!=3 ? Weff[s][k][jj] : 0    (Weff = Wmp[s] @ Wih^T)
//   k>=128: g!=2 ? Whh[jj][k-128] : 0
__global__ void k_prepB(const float* __restrict__ Wmp, const float* __restrict__ Wih,
                        const float* __restrict__ Whh, _Float16* __restrict__ Bsw) {
    __shared__ float wih[HD];
    int b = blockIdx.x;          // s*512 + c
    int s = b >> 9;
    int c = b & 511;
    int g = c >> 7;
    int j = c & 127;
    int jj = (g < 2) ? c : (j + 256);
    int k = threadIdx.x;         // 0..255
    if (k < HD) wih[k] = Wih[(size_t)jj * HD + k];
    __syncthreads();
    float val = 0.f;
    if (k < 128) {
        if (g != 3) {
            const float* wm = Wmp + ((size_t)s * HD + k) * HD;
            float acc = 0.f;
#pragma unroll 8
            for (int t = 0; t < HD; ++t) acc += wm[t] * wih[t];
            val = acc;
        }
    } else {
        if (g != 2) val = Whh[(size_t)jj * HD + (k - 128)];
    }
    int l16 = c & 15, sub = (c >> 4) & 1, w = (c >> 5) & 3;
    int t = g * 2 + sub;
    int p = k >> 5, quad = (k >> 3) & 3, je = k & 7;
    size_t idx = (size_t)s * 131072 + ((size_t)((w * 8 + t) * 8 + p) * 64 + quad * 16 + l16) * 8 + je;
    Bsw[idx] = (_Float16)val;
}

// ---------------- W_in prep: fragment-order hi/lo fp16 ----------------
__global__ void k_prepWin(const float* __restrict__ Win,
                          _Float16* __restrict__ BihW, _Float16* __restrict__ BilW) {
    int gid = blockIdx.x * 256 + threadIdx.x;   // 0..8191
    int jj = gid & 7;
    int lane = (gid >> 3) & 63;
    int p = (gid >> 9) & 1;
    int t = (gid >> 10) & 7;
    int k = p * 32 + (lane >> 4) * 8 + jj;
    int col = t * 16 + (lane & 15);
    float val = Win[(size_t)k * HD + col];
    _Float16 hi = (_Float16)val;
    BihW[gid] = hi;
    BilW[gid] = (_Float16)(val - (float)hi);
}

// ---------------- input layer (MFMA): h = tanh(x @ W_in), fp16 out ----------------
__global__ void __launch_bounds__(256) k_input(const float* __restrict__ x,
                                               const _Float16* __restrict__ BihW,
                                               const _Float16* __restrict__ BilW,
                                               _Float16* __restrict__ H) {
    __shared__ _Float16 Xh[64 * 64];
    __shared__ _Float16 Xl[64 * 64];
    __shared__ _Float16 Oh[64 * 128];
    int tid = threadIdx.x;
    int w = tid >> 6, lane = tid & 63;
    int quad = lane >> 4, l16 = lane & 15;
    int m0 = blockIdx.x * 64;

#pragma unroll
    for (int it = 0; it < 4; ++it) {
        int c = it * 256 + tid;          // 1024 chunks of 4 floats
        int row = c >> 4, cc = c & 15;
        int grow = m0 + row; if (grow >= NN) grow = NN - 1;
        float4 v = ((const float4*)(x + (size_t)grow * FIN))[cc];
        f16x4 vh, vl;
        vh[0] = (_Float16)v.x; vl[0] = (_Float16)(v.x - (float)vh[0]);
        vh[1] = (_Float16)v.y; vl[1] = (_Float16)(v.y - (float)vh[1]);
        vh[2] = (_Float16)v.z; vl[2] = (_Float16)(v.z - (float)vh[2]);
        vh[3] = (_Float16)v.w; vl[3] = (_Float16)(v.w - (float)vh[3]);
        int ld = row * 64 + ((((cc >> 1) ^ (row & 7)) << 3)) + (cc & 1) * 4;
        *(f16x4*)(&Xh[ld]) = vh;
        *(f16x4*)(&Xl[ld]) = vl;
    }
    __syncthreads();

    f32x4 acc[4][2];
#pragma unroll
    for (int mi = 0; mi < 4; ++mi) { acc[mi][0] = (f32x4){0,0,0,0}; acc[mi][1] = (f32x4){0,0,0,0}; }

#pragma unroll
    for (int p = 0; p < 2; ++p) {
        int ch = p * 4 + quad;
        f16x8 ah[4], al[4];
#pragma unroll
        for (int mi = 0; mi < 4; ++mi) {
            int r = mi * 16 + l16;
            int li = r * 64 + ((ch ^ (r & 7)) << 3);
            ah[mi] = *(const f16x8*)(&Xh[li]);
            al[mi] = *(const f16x8*)(&Xl[li]);
        }
#pragma unroll
        for (int t2 = 0; t2 < 2; ++t2) {
            int t = w * 2 + t2;
            f16x8 bh = *(const f16x8*)(BihW + ((size_t)(t * 2 + p) * 64 + lane) * 8);
            f16x8 blv = *(const f16x8*)(BilW + ((size_t)(t * 2 + p) * 64 + lane) * 8);
#pragma unroll
            for (int mi = 0; mi < 4; ++mi) {
                acc[mi][t2] = __builtin_amdgcn_mfma_f32_16x16x32_f16(ah[mi], bh, acc[mi][t2], 0, 0, 0);
                acc[mi][t2] = __builtin_amdgcn_mfma_f32_16x16x32_f16(ah[mi], blv, acc[mi][t2], 0, 0, 0);
                acc[mi][t2] = __builtin_amdgcn_mfma_f32_16x16x32_f16(al[mi], bh, acc[mi][t2], 0, 0, 0);
            }
        }
    }

#pragma unroll
    for (int t2 = 0; t2 < 2; ++t2) {
        int j = (w * 2 + t2) * 16 + l16;
#pragma unroll
        for (int mi = 0; mi < 4; ++mi) {
#pragma unroll
            for (int reg = 0; reg < 4; ++reg) {
                int row = mi * 16 + quad * 4 + reg;
                Oh[lidx(row, j)] = (_Float16)tanhfast(acc[mi][t2][reg]);
            }
        }
    }
    __syncthreads();
#pragma unroll
    for (int it = 0; it < 4; ++it) {
        int c = it * 256 + tid;
        int row = c >> 4, kc = c & 15;
        int grow = m0 + row;
        if (grow < NN) {
            int ld = row * 128 + ((kc ^ (row & 15)) << 3);
            *(f16x8*)(H + (size_t)grow * HD + kc * 8) = *(const f16x8*)(&Oh[ld]);
        }
    }
}

// ---------------- aggregation: S[v] = sum_{in-edges} H[src], fp16 out ----------------
// [R2 post-mortem: fusing this into the GEMM (k_step) REGRESSED 161->188us/step.
//  The gather is latency-bound and needs max TLP: 25000 blocks/100K waves here vs
//  1563 blocks/8 waves-per-CU fused. KEEP SPLIT.]
__global__ void k_agg(const _Float16* __restrict__ H, const int* __restrict__ indptr,
                      const int* __restrict__ csr, _Float16* __restrict__ Shi) {
    int v = blockIdx.x * 4 + (threadIdx.x >> 6);
    int lane = threadIdx.x & 63;
    int slot = lane >> 4;
    int cg = lane & 15;
    const _Float16* hp = H + cg * 8;
    int s = indptr[v], e = indptr[v + 1];
    float a0 = 0.f, a1 = 0.f, a2 = 0.f, a3 = 0.f, a4 = 0.f, a5 = 0.f, a6 = 0.f, a7 = 0.f;
    int i = s + slot;
    for (; i + 12 < e; i += 16) {
        int u0 = csr[i], u1 = csr[i + 4], u2 = csr[i + 8], u3 = csr[i + 12];
        f16x8 t0 = *(const f16x8*)(hp + (size_t)u0 * HD);
        f16x8 t1 = *(const f16x8*)(hp + (size_t)u1 * HD);
        f16x8 t2 = *(const f16x8*)(hp + (size_t)u2 * HD);
        f16x8 t3 = *(const f16x8*)(hp + (size_t)u3 * HD);
        a0 += (float)t0[0] + (float)t1[0] + (float)t2[0] + (float)t3[0];
        a1 += (float)t0[1] + (float)t1[1] + (float)t2[1] + (float)t3[1];
        a2 += (float)t0[2] + (float)t1[2] + (float)t2[2] + (float)t3[2];
        a3 += (float)t0[3] + (float)t1[3] + (float)t2[3] + (float)t3[3];
        a4 += (float)t0[4] + (float)t1[4] + (float)t2[4] + (float)t3[4];
        a5 += (float)t0[5] + (float)t1[5] + (float)t2[5] + (float)t3[5];
        a6 += (float)t0[6] + (float)t1[6] + (float)t2[6] + (float)t3[6];
        a7 += (float)t0[7] + (float)t1[7] + (float)t2[7] + (float)t3[7];
    }
    for (; i < e; i += 4) {
        int u0 = csr[i];
        f16x8 t0 = *(const f16x8*)(hp + (size_t)u0 * HD);
        a0 += (float)t0[0]; a1 += (float)t0[1]; a2 += (float)t0[2]; a3 += (float)t0[3];
        a4 += (float)t0[4]; a5 += (float)t0[5]; a6 += (float)t0[6]; a7 += (float)t0[7];
    }
    a0 += __shfl_down(a0, 32); a1 += __shfl_down(a1, 32);
    a2 += __shfl_down(a2, 32); a3 += __shfl_down(a3, 32);
    a4 += __shfl_down(a4, 32); a5 += __shfl_down(a5, 32);
    a6 += __shfl_down(a6, 32); a7 += __shfl_down(a7, 32);
    a0 += __shfl_down(a0, 16); a1 += __shfl_down(a1, 16);
    a2 += __shfl_down(a2, 16); a3 += __shfl_down(a3, 16);
    a4 += __shfl_down(a4, 16); a5 += __shfl_down(a5, 16);
    a6 += __shfl_down(a6, 16); a7 += __shfl_down(a7, 16);
    if (lane < 16) {
        f16x8 o;
        o[0] = (_Float16)a0; o[1] = (_Float16)a1; o[2] = (_Float16)a2; o[3] = (_Float16)a3;
        o[4] = (_Float16)a4; o[5] = (_Float16)a5; o[6] = (_Float16)a6; o[7] = (_Float16)a7;
        *(f16x8*)(Shi + (size_t)v * HD + cg * 8) = o;
    }
}

// ---------------- fused MFMA GEMM + GRU gates (H fp16, in place) ----------------
// [R2 counters on 64-row version: acc[4][8]=128 AGPR + 84 VGPR = 212 regs ->
//  2 waves/SIMD = 2 blocks/CU (Occupancy 24%), phases serialize, 1.9TB/s on a
//  streaming kernel. R3: 32-row tile -> acc[2][8]=64 AGPR, ~164 regs ->
//  3 waves/SIMD = 12 waves/CU; H staged via regs so S-phase MFMAs hide H load
//  latency. Grid 3125 (=NN/32 exact, no tail).]
__global__ void __launch_bounds__(256, 3) k_ggemm(
        const _Float16* __restrict__ Shi, _Float16* __restrict__ H,
        const _Float16* __restrict__ Bsw,
        const float* __restrict__ bih, const float* __restrict__ bhh) {
    __shared__ _Float16 Sl[32 * 128];
    __shared__ _Float16 Hh[32 * 128];
    int tid = threadIdx.x;
    int w = tid >> 6, lane = tid & 63;
    int quad = lane >> 4, l16 = lane & 15;
    int m0 = blockIdx.x * 32;

    // stage: Sl -> LDS now; H -> regs (LDS write deferred under S-phase MFMAs)
    f16x8 hreg[2];
#pragma unroll
    for (int it = 0; it < 2; ++it) {
        int c = it * 256 + tid;
        int row = c >> 4, kc = c & 15;
        int grow = m0 + row;
        size_t gsrc = (size_t)grow * HD + kc * 8;
        int ld = row * 128 + ((kc ^ (row & 15)) << 3);
        *(f16x8*)(&Sl[ld]) = *(const f16x8*)(Shi + gsrc);
        hreg[it] = *(const f16x8*)(H + gsrc);
    }
    __syncthreads();

    f32x4 acc[2][8];
#pragma unroll
    for (int mi = 0; mi < 2; ++mi)
#pragma unroll
        for (int t = 0; t < 8; ++t) acc[mi][t] = (f32x4){0.f, 0.f, 0.f, 0.f};

    const _Float16* bw = Bsw + (size_t)(w * 8) * 8 * 512 + lane * 8;

    // S phases (gates r,z,i_n -> t=0..5); H global loads still in flight
#pragma unroll
    for (int p = 0; p < 4; ++p) {
        f16x8 a[2];
#pragma unroll
        for (int mi = 0; mi < 2; ++mi)
            a[mi] = *(const f16x8*)(&Sl[lidx(mi * 16 + l16, p * 32 + quad * 8)]);
#pragma unroll
        for (int t = 0; t < 6; ++t) {
            f16x8 b = *(const f16x8*)(bw + (size_t)(t * 8 + p) * 512);
#pragma unroll
            for (int mi = 0; mi < 2; ++mi)
                acc[mi][t] = __builtin_amdgcn_mfma_f32_16x16x32_f16(a[mi], b, acc[mi][t], 0, 0, 0);
        }
    }

    // now commit H regs -> LDS
#pragma unroll
    for (int it = 0; it < 2; ++it) {
        int c = it * 256 + tid;
        int row = c >> 4, kc = c & 15;
        int ld = row * 128 + ((kc ^ (row & 15)) << 3);
        *(f16x8*)(&Hh[ld]) = hreg[it];
    }
    __syncthreads();

    // H phases (gates r,z,h_n -> t={0,1,2,3,6,7})
#pragma unroll
    for (int p = 0; p < 4; ++p) {
        f16x8 a[2];
#pragma unroll
        for (int mi = 0; mi < 2; ++mi)
            a[mi] = *(const f16x8*)(&Hh[lidx(mi * 16 + l16, p * 32 + quad * 8)]);
#pragma unroll
        for (int tt = 0; tt < 6; ++tt) {
            int t = (tt < 4) ? tt : (tt + 2);
            f16x8 b = *(const f16x8*)(bw + (size_t)(t * 8 + p + 4) * 512);
#pragma unroll
            for (int mi = 0; mi < 2; ++mi)
                acc[mi][t] = __builtin_amdgcn_mfma_f32_16x16x32_f16(a[mi], b, acc[mi][t], 0, 0, 0);
        }
    }

    __syncthreads();   // all H-LDS A-reads done before epilogue overwrites Hh

    // epilogue: gates; in-place RMW on Hh (each li touched by exactly one thread)
#pragma unroll
    for (int ns = 0; ns < 2; ++ns) {
        int j = w * 32 + ns * 16 + l16;
        float br  = bih[j]       + bhh[j];
        float bz  = bih[j + 128] + bhh[j + 128];
        float bin = bih[j + 256];
        float bhn = bhh[j + 256];
#pragma unroll
        for (int mi = 0; mi < 2; ++mi) {
#pragma unroll
            for (int reg = 0; reg < 4; ++reg) {
                int row = mi * 16 + quad * 4 + reg;
                int li = lidx(row, j);
                float hold = (float)Hh[li];
                float r = sigm(acc[mi][0 + ns][reg] + br);
                float z = sigm(acc[mi][2 + ns][reg] + bz);
                float n = tanhfast(acc[mi][4 + ns][reg] + bin + r * (acc[mi][6 + ns][reg] + bhn));
                Hh[li] = (_Float16)((1.f - z) * n + z * hold);
            }
        }
    }
    __syncthreads();

#pragma unroll
    for (int it = 0; it < 2; ++it) {
        int c = it * 256 + tid;
        int row = c >> 4, kc = c & 15;
        int grow = m0 + row;
        int ld = row * 128 + ((kc ^ (row & 15)) << 3);
        *(f16x8*)(H + (size_t)grow * HD + kc * 8) = *(const f16x8*)(&Hh[ld]);
    }
}

// ---------------- pooling + head ----------------
__global__ void k_ginit(int* __restrict__ gs, int* __restrict__ ge) {
    int g = threadIdx.x;
    if (g < NG) { gs[g] = 0; ge[g] = 0; }
}

__global__ void k_bounds(const int* __restrict__ batch, int* __restrict__ gs, int* __restrict__ ge) {
    int i = blockIdx.x * 256 + threadIdx.x;
    if (i >= NN) return;
    int b = batch[i];
    if (i == 0 || batch[i - 1] != b) gs[b] = i;
    if (i == NN - 1 || batch[i + 1] != b) ge[b] = i + 1;
}

__global__ void k_pool(const _Float16* __restrict__ H,
                       const int* __restrict__ gs, const int* __restrict__ ge,
                       const float* __restrict__ Wp, const float* __restrict__ bp,
                       float* __restrict__ out) {
    __shared__ float red[HD];
    int g = blockIdx.x, tid = threadIdx.x;
    int s = gs[g], e = ge[g];
    float acc = 0.f;
    for (int n = s; n < e; ++n) acc += (float)H[(size_t)n * HD + tid];
    int cnt = e - s;
    float pooled = acc / (float)(cnt > 0 ? cnt : 1);
    red[tid] = fmaxf(pooled, 0.f) * Wp[tid];
    __syncthreads();
    for (int off = 64; off > 0; off >>= 1) {
        if (tid < off) red[tid] += red[tid + off];
        __syncthreads();
    }
    if (tid == 0) out[g] = red[0] + bp[0];
}

extern "C" void kernel_launch(void* const* d_in, const int* in_sizes, int n_in,
                              void* d_out, int out_size, void* d_ws, size_t ws_size,
                              hipStream_t stream) {
    const float* x   = (const float*)d_in[0];
    const int*   ei  = (const int*)d_in[1];
    const int*   bat = (const int*)d_in[2];
    const float* Win = (const float*)d_in[3];
    const float* Wmp = (const float*)d_in[4];
    const float* Wih = (const float*)d_in[5];
    const float* Whh = (const float*)d_in[6];
    const float* bih = (const float*)d_in[7];
    const float* bhh = (const float*)d_in[8];
    const float* Wp  = (const float*)d_in[9];
    const float* bp  = (const float*)d_in[10];
    float* out = (float*)d_out;

    const int* esrc = ei;
    const int* edst = ei + NE;

    char* w = (char*)d_ws;
    _Float16* H   = (_Float16*)w; w += (size_t)NN * HD * 2;
    _Float16* Shi = (_Float16*)w; w += (size_t)NN * HD * 2;
    _Float16* Bsw = (_Float16*)w; w += (size_t)NSTEP * 131072 * 2;
    _Float16* BihW = (_Float16*)w; w += 8192 * 2;
    _Float16* BilW = (_Float16*)w; w += 8192 * 2;
    int* indptr  = (int*)w;   w += 400128;
    int* cursor  = (int*)w;   w += 400128;   // counts during scan; bucket cursors after
    int* csr     = (int*)w;   w += (size_t)NE * 4;
    int* aux     = (int*)w;   w += 512;
    int* gs      = (int*)w;   w += NG * 4;
    int* ge      = (int*)w;   w += NG * 4;

    // pairs buffer aliases Shi (12.8MB; consumed by k_fill2 before first k_agg)
    int2* pairs = (int2*)Shi;
    int*  bcur  = cursor;    // counts no longer needed after scan3

    // CSR build: count -> scan -> bucket-bin -> dense per-bucket fill
    hipMemsetAsync(cursor, 0, (size_t)NN * 4, stream);
    k_count<<<NE / 256, 256, 0, stream>>>(edst, cursor);
    k_scan1<<<NBLK, 256, 0, stream>>>(cursor, indptr, aux);
    k_scan2<<<1, 128, 0, stream>>>(aux);
    k_scan3<<<NBLK, 256, 0, stream>>>(indptr, aux);
    k_bcinit<<<(NBUCK + 255) / 256, 256, 0, stream>>>(indptr, bcur);
    k_bin<<<BINBLK, 256, 0, stream>>>(esrc, edst, bcur, pairs);
    k_fill2<<<NBUCK, 256, 0, stream>>>(pairs, indptr, csr);

    // weight prep + input layer
    k_prepB<<<NSTEP * 512, 256, 0, stream>>>(Wmp, Wih, Whh, Bsw);
    k_prepWin<<<32, 256, 0, stream>>>(Win, BihW, BilW);
    k_input<<<(NN + 63) / 64, 256, 0, stream>>>(x, BihW, BilW, H);

    // 6 message-passing + fused GEMM/GRU steps (H updated in place)
    for (int st = 0; st < NSTEP; ++st) {
        k_agg<<<NN / 4, 256, 0, stream>>>(H, indptr, csr, Shi);
        k_ggemm<<<NN / 32, 256, 0, stream>>>(Shi, H,
                                             Bsw + (size_t)st * 131072,
                                             bih, bhh);
    }

    // pooling + head
    k_ginit<<<1, NG, 0, stream>>>(gs, ge);
    k_bounds<<<(NN + 255) / 256, 256, 0, stream>>>(bat, gs, ge);
    k_pool<<<NG, HD, 0, stream>>>(H, gs, ge, Wp, bp, out);
}

// Round 4
// 869.684 us; speedup vs baseline: 1.5767x; 1.0673x over previous
//
#include <hip/hip_runtime.h>

#define NN 100000
#define NE 1600000
#define NG 512
#define FIN 64
#define HD 128
#define NSTEP 6
#define SCHUNK 1024
#define NBLK 98    // ceil(NN/SCHUNK)

// ---- bucketed CSR fill geometry ----
#define BROWS 128               // dst nodes per bucket
#define NBUCK 782               // ceil(NN/BROWS)
#define EPER 16                 // edges per thread in k_bin
#define BINBLK 391              // ceil(NE / (256*EPER))

typedef _Float16 f16x8 __attribute__((ext_vector_type(8)));
typedef _Float16 f16x4 __attribute__((ext_vector_type(4)));
typedef float    f32x4 __attribute__((ext_vector_type(4)));

__device__ __forceinline__ float sigm(float x) { return 1.f / (1.f + __expf(-x)); }
__device__ __forceinline__ float tanhfast(float x) { return 2.f / (1.f + __expf(-2.f * x)) - 1.f; }

// LDS tile index with XOR swizzle (128-col tiles, 16B chunks)
__device__ __forceinline__ int lidx(int r, int col) {
    return r * 128 + ((((col >> 3) ^ (r & 15)) << 3) | (col & 7));
}

// ---------------- CSR build ----------------
__global__ void k_count(const int* __restrict__ dst, int* __restrict__ counts) {
    int e = blockIdx.x * 256 + threadIdx.x;
    if (e < NE) atomicAdd(&counts[dst[e]], 1);
}

__global__ void k_scan1(const int* __restrict__ counts, int* __restrict__ indptr, int* __restrict__ aux) {
    __shared__ int sh[256];
    int blk = blockIdx.x, tid = threadIdx.x;
    int base = blk * SCHUNK + tid * 4;
    int v0 = 0, v1 = 0, v2 = 0, v3 = 0;
    if (base + 0 < NN) v0 = counts[base + 0];
    if (base + 1 < NN) v1 = counts[base + 1];
    if (base + 2 < NN) v2 = counts[base + 2];
    if (base + 3 < NN) v3 = counts[base + 3];
    int tsum = v0 + v1 + v2 + v3;
    sh[tid] = tsum;
    __syncthreads();
    for (int off = 1; off < 256; off <<= 1) {
        int t = (tid >= off) ? sh[tid - off] : 0;
        __syncthreads();
        sh[tid] += t;
        __syncthreads();
    }
    int excl = sh[tid] - tsum;
    if (base + 0 < NN) indptr[base + 0] = excl;
    if (base + 1 < NN) indptr[base + 1] = excl + v0;
    if (base + 2 < NN) indptr[base + 2] = excl + v0 + v1;
    if (base + 3 < NN) indptr[base + 3] = excl + v0 + v1 + v2;
    if (tid == 255) aux[blk] = sh[255];
}

__global__ void k_scan2(int* __restrict__ aux) {
    __shared__ int sh[128];
    int tid = threadIdx.x;
    int v = (tid < NBLK) ? aux[tid] : 0;
    sh[tid] = v;
    __syncthreads();
    for (int off = 1; off < 128; off <<= 1) {
        int t = (tid >= off) ? sh[tid - off] : 0;
        __syncthreads();
        sh[tid] += t;
        __syncthreads();
    }
    if (tid < NBLK) aux[tid] = sh[tid] - v;
}

__global__ void k_scan3(int* __restrict__ indptr, const int* __restrict__ aux) {
    int blk = blockIdx.x, tid = threadIdx.x;
    int off = aux[blk];
    int base = blk * SCHUNK + tid * 4;
#pragma unroll
    for (int i = 0; i < 4; ++i) {
        int idx = base + i;
        if (idx < NN) indptr[idx] += off;
    }
    if (blk == 0 && tid == 0) indptr[NN] = NE;
}

// [R0: direct-scatter fill = 105MB write-amp, 126us. R1: this bucketed scheme
//  (per-BLOCK reservation, dense per-bucket windows) = ~25us total. KEEP.]

// bucket cursors <- indptr at bucket boundaries
__global__ void k_bcinit(const int* __restrict__ indptr, int* __restrict__ bcur) {
    int b = blockIdx.x * 256 + threadIdx.x;
    if (b < NBUCK) bcur[b] = indptr[b * BROWS];
}

// phase 1: bin (src,dst) pairs into per-bucket append regions
__global__ void __launch_bounds__(256) k_bin(const int* __restrict__ src, const int* __restrict__ dst,
                                             int* __restrict__ bcur, int2* __restrict__ pairs) {
    __shared__ int hist[NBUCK];
    __shared__ int base[NBUCK];
    int tid = threadIdx.x;
    for (int i = tid; i < NBUCK; i += 256) hist[i] = 0;
    __syncthreads();
    int e0 = blockIdx.x * (256 * EPER) + tid;
    int s[EPER], d[EPER], rk[EPER];
#pragma unroll
    for (int k = 0; k < EPER; ++k) {
        int e = e0 + k * 256;
        if (e < NE) {
            s[k] = src[e];
            d[k] = dst[e];
            rk[k] = atomicAdd(&hist[d[k] >> 7], 1);   // LDS atomic: local rank within (block,bucket)
        }
    }
    __syncthreads();
    for (int i = tid; i < NBUCK; i += 256) {
        int c = hist[i];
        base[i] = c ? atomicAdd(&bcur[i], c) : 0;     // one global atomic per (block,bucket)
    }
    __syncthreads();
#pragma unroll
    for (int k = 0; k < EPER; ++k) {
        int e = e0 + k * 256;
        if (e < NE) pairs[base[d[k] >> 7] + rk[k]] = make_int2(s[k], d[k]);
    }
}

// phase 2: one block per bucket; dense contiguous csr window per bucket
__global__ void __launch_bounds__(256) k_fill2(const int2* __restrict__ pairs,
                                               const int* __restrict__ indptr, int* __restrict__ csr) {
    __shared__ int cnt[BROWS];
    __shared__ int ip[BROWS];
    int b = blockIdx.x, tid = threadIdx.x;
    int n0 = b * BROWS;
    if (tid < BROWS) {
        cnt[tid] = 0;
        ip[tid] = (n0 + tid < NN) ? indptr[n0 + tid] : NE;
    }
    __syncthreads();
    int s = indptr[n0];
    int nend = n0 + BROWS; if (nend > NN) nend = NN;
    int e = indptr[nend];
    for (int i = s + tid; i < e; i += 256) {
        int2 p = pairs[i];
        int li = p.y & (BROWS - 1);                    // p.y - n0 (n0 is a multiple of 128)
        int r = atomicAdd(&cnt[li], 1);
        csr[ip[li] + r] = p.x;
    }
}

// ---------------- B prep (GRU weights), swizzled to MFMA fragment order ----------------
// Logical Bcat[c][k]: c=0..511 (g=c>>7: 0=r,1=z,2=i_n,3=h_n; j=c&127), k=0..255.
//   k<128:  g!=3 ? Weff[s][k][jj] : 0    (Weff = Wmp[s] @ Wih^T)
//   k>=128: g!=2 ? Whh[jj][k-128] : 0
__global__ void k_prepB(const float* __restrict__ Wmp, const float* __restrict__ Wih,
                        const float* __restrict__ Whh, _Float16* __restrict__ Bsw) {
    __shared__ float wih[HD];
    int b = blockIdx.x;          // s*512 + c
    int s = b >> 9;
    int c = b & 511;
    int g = c >> 7;
    int j = c & 127;
    int jj = (g < 2) ? c : (j + 256);
    int k = threadIdx.x;         // 0..255
    if (k < HD) wih[k] = Wih[(size_t)jj * HD + k];
    __syncthreads();
    float val = 0.f;
    if (k < 128) {
        if (g != 3) {
            const float* wm = Wmp + ((size_t)s * HD + k) * HD;
            float acc = 0.f;
#pragma unroll 8
            for (int t = 0; t < HD; ++t) acc += wm[t] * wih[t];
            val = acc;
        }
    } else {
        if (g != 2) val = Whh[(size_t)jj * HD + (k - 128)];
    }
    int l16 = c & 15, sub = (c >> 4) & 1, w = (c >> 5) & 3;
    int t = g * 2 + sub;
    int p = k >> 5, quad = (k >> 3) & 3, je = k & 7;
    size_t idx = (size_t)s * 131072 + ((size_t)((w * 8 + t) * 8 + p) * 64 + quad * 16 + l16) * 8 + je;
    Bsw[idx] = (_Float16)val;
}

// ---------------- W_in prep: fragment-order hi/lo fp16 ----------------
__global__ void k_prepWin(const float* __restrict__ Win,
                          _Float16* __restrict__ BihW, _Float16* __restrict__ BilW) {
    int gid = blockIdx.x * 256 + threadIdx.x;   // 0..8191
    int jj = gid & 7;
    int lane = (gid >> 3) & 63;
    int p = (gid >> 9) & 1;
    int t = (gid >> 10) & 7;
    int k = p * 32 + (lane >> 4) * 8 + jj;
    int col = t * 16 + (lane & 15);
    float val = Win[(size_t)k * HD + col];
    _Float16 hi = (_Float16)val;
    BihW[gid] = hi;
    BilW[gid] = (_Float16)(val - (float)hi);
}

// ---------------- input layer (MFMA): h = tanh(x @ W_in), fp16 out ----------------
__global__ void __launch_bounds__(256) k_input(const float* __restrict__ x,
                                               const _Float16* __restrict__ BihW,
                                               const _Float16* __restrict__ BilW,
                                               _Float16* __restrict__ H) {
    __shared__ _Float16 Xh[64 * 64];
    __shared__ _Float16 Xl[64 * 64];
    __shared__ _Float16 Oh[64 * 128];
    int tid = threadIdx.x;
    int w = tid >> 6, lane = tid & 63;
    int quad = lane >> 4, l16 = lane & 15;
    int m0 = blockIdx.x * 64;

#pragma unroll
    for (int it = 0; it < 4; ++it) {
        int c = it * 256 + tid;          // 1024 chunks of 4 floats
        int row = c >> 4, cc = c & 15;
        int grow = m0 + row; if (grow >= NN) grow = NN - 1;
        float4 v = ((const float4*)(x + (size_t)grow * FIN))[cc];
        f16x4 vh, vl;
        vh[0] = (_Float16)v.x; vl[0] = (_Float16)(v.x - (float)vh[0]);
        vh[1] = (_Float16)v.y; vl[1] = (_Float16)(v.y - (float)vh[1]);
        vh[2] = (_Float16)v.z; vl[2] = (_Float16)(v.z - (float)vh[2]);
        vh[3] = (_Float16)v.w; vl[3] = (_Float16)(v.w - (float)vh[3]);
        int ld = row * 64 + ((((cc >> 1) ^ (row & 7)) << 3)) + (cc & 1) * 4;
        *(f16x4*)(&Xh[ld]) = vh;
        *(f16x4*)(&Xl[ld]) = vl;
    }
    __syncthreads();

    f32x4 acc[4][2];
#pragma unroll
    for (int mi = 0; mi < 4; ++mi) { acc[mi][0] = (f32x4){0,0,0,0}; acc[mi][1] = (f32x4){0,0,0,0}; }

#pragma unroll
    for (int p = 0; p < 2; ++p) {
        int ch = p * 4 + quad;
        f16x8 ah[4], al[4];
#pragma unroll
        for (int mi = 0; mi < 4; ++mi) {
            int r = mi * 16 + l16;
            int li = r * 64 + ((ch ^ (r & 7)) << 3);
            ah[mi] = *(const f16x8*)(&Xh[li]);
            al[mi] = *(const f16x8*)(&Xl[li]);
        }
#pragma unroll
        for (int t2 = 0; t2 < 2; ++t2) {
            int t = w * 2 + t2;
            f16x8 bh = *(const f16x8*)(BihW + ((size_t)(t * 2 + p) * 64 + lane) * 8);
            f16x8 blv = *(const f16x8*)(BilW + ((size_t)(t * 2 + p) * 64 + lane) * 8);
#pragma unroll
            for (int mi = 0; mi < 4; ++mi) {
                acc[mi][t2] = __builtin_amdgcn_mfma_f32_16x16x32_f16(ah[mi], bh, acc[mi][t2], 0, 0, 0);
                acc[mi][t2] = __builtin_amdgcn_mfma_f32_16x16x32_f16(ah[mi], blv, acc[mi][t2], 0, 0, 0);
                acc[mi][t2] = __builtin_amdgcn_mfma_f32_16x16x32_f16(al[mi], bh, acc[mi][t2], 0, 0, 0);
            }
        }
    }

#pragma unroll
    for (int t2 = 0; t2 < 2; ++t2) {
        int j = (w * 2 + t2) * 16 + l16;
#pragma unroll
        for (int mi = 0; mi < 4; ++mi) {
#pragma unroll
            for (int reg = 0; reg < 4; ++reg) {
                int row = mi * 16 + quad * 4 + reg;
                Oh[lidx(row, j)] = (_Float16)tanhfast(acc[mi][t2][reg]);
            }
        }
    }
    __syncthreads();
#pragma unroll
    for (int it = 0; it < 4; ++it) {
        int c = it * 256 + tid;
        int row = c >> 4, kc = c & 15;
        int grow = m0 + row;
        if (grow < NN) {
            int ld = row * 128 + ((kc ^ (row & 15)) << 3);
            *(f16x8*)(H + (size_t)grow * HD + kc * 8) = *(const f16x8*)(&Oh[ld]);
        }
    }
}

// ---------------- aggregation: S[v] = sum_{in-edges} H[src], fp16 out ----------------
// [R2 post-mortem: fusing this into the GEMM (k_step) REGRESSED 161->188us/step.
//  The gather is latency-bound and needs max TLP: 25000 blocks/100K waves here vs
//  1563 blocks/8 waves-per-CU fused. KEEP SPLIT.]
__global__ void k_agg(const _Float16* __restrict__ H, const int* __restrict__ indptr,
                      const int* __restrict__ csr, _Float16* __restrict__ Shi) {
    int v = blockIdx.x * 4 + (threadIdx.x >> 6);
    int lane = threadIdx.x & 63;
    int slot = lane >> 4;
    int cg = lane & 15;
    const _Float16* hp = H + cg * 8;
    int s = indptr[v], e = indptr[v + 1];
    float a0 = 0.f, a1 = 0.f, a2 = 0.f, a3 = 0.f, a4 = 0.f, a5 = 0.f, a6 = 0.f, a7 = 0.f;
    int i = s + slot;
    for (; i + 12 < e; i += 16) {
        int u0 = csr[i], u1 = csr[i + 4], u2 = csr[i + 8], u3 = csr[i + 12];
        f16x8 t0 = *(const f16x8*)(hp + (size_t)u0 * HD);
        f16x8 t1 = *(const f16x8*)(hp + (size_t)u1 * HD);
        f16x8 t2 = *(const f16x8*)(hp + (size_t)u2 * HD);
        f16x8 t3 = *(const f16x8*)(hp + (size_t)u3 * HD);
        a0 += (float)t0[0] + (float)t1[0] + (float)t2[0] + (float)t3[0];
        a1 += (float)t0[1] + (float)t1[1] + (float)t2[1] + (float)t3[1];
        a2 += (float)t0[2] + (float)t1[2] + (float)t2[2] + (float)t3[2];
        a3 += (float)t0[3] + (float)t1[3] + (float)t2[3] + (float)t3[3];
        a4 += (float)t0[4] + (float)t1[4] + (float)t2[4] + (float)t3[4];
        a5 += (float)t0[5] + (float)t1[5] + (float)t2[5] + (float)t3[5];
        a6 += (float)t0[6] + (float)t1[6] + (float)t2[6] + (float)t3[6];
        a7 += (float)t0[7] + (float)t1[7] + (float)t2[7] + (float)t3[7];
    }
    for (; i < e; i += 4) {
        int u0 = csr[i];
        f16x8 t0 = *(const f16x8*)(hp + (size_t)u0 * HD);
        a0 += (float)t0[0]; a1 += (float)t0[1]; a2 += (float)t0[2]; a3 += (float)t0[3];
        a4 += (float)t0[4]; a5 += (float)t0[5]; a6 += (float)t0[6]; a7 += (float)t0[7];
    }
    a0 += __shfl_down(a0, 32); a1 += __shfl_down(a1, 32);
    a2 += __shfl_down(a2, 32); a3 += __shfl_down(a3, 32);
    a4 += __shfl_down(a4, 32); a5 += __shfl_down(a5, 32);
    a6 += __shfl_down(a6, 32); a7 += __shfl_down(a7, 32);
    a0 += __shfl_down(a0, 16); a1 += __shfl_down(a1, 16);
    a2 += __shfl_down(a2, 16); a3 += __shfl_down(a3, 16);
    a4 += __shfl_down(a4, 16); a5 += __shfl_down(a5, 16);
    a6 += __shfl_down(a6, 16); a7 += __shfl_down(a7, 16);
    if (lane < 16) {
        f16x8 o;
        o[0] = (_Float16)a0; o[1] = (_Float16)a1; o[2] = (_Float16)a2; o[3] = (_Float16)a3;
        o[4] = (_Float16)a4; o[5] = (_Float16)a5; o[6] = (_Float16)a6; o[7] = (_Float16)a7;
        *(f16x8*)(Shi + (size_t)v * HD + cg * 8) = o;
    }
}

// ---------------- fused MFMA GEMM + GRU gates (H fp16, in place) ----------------
// [R2: 64-row tile = 212 regs -> 2 blocks/CU (Occ 24%), 81us. R3: 32-row tile ->
//  acc[2][8], 3 waves/SIMD, H staged via regs under S-phase MFMAs -> out of top-5
//  (<68us). KEEP.]
__global__ void __launch_bounds__(256, 3) k_ggemm(
        const _Float16* __restrict__ Shi, _Float16* __restrict__ H,
        const _Float16* __restrict__ Bsw,
        const float* __restrict__ bih, const float* __restrict__ bhh) {
    __shared__ _Float16 Sl[32 * 128];
    __shared__ _Float16 Hh[32 * 128];
    int tid = threadIdx.x;
    int w = tid >> 6, lane = tid & 63;
    int quad = lane >> 4, l16 = lane & 15;
    int m0 = blockIdx.x * 32;

    // stage: Sl -> LDS now; H -> regs (LDS write deferred under S-phase MFMAs)
    f16x8 hreg[2];
#pragma unroll
    for (int it = 0; it < 2; ++it) {
        int c = it * 256 + tid;
        int row = c >> 4, kc = c & 15;
        int grow = m0 + row;
        size_t gsrc = (size_t)grow * HD + kc * 8;
        int ld = row * 128 + ((kc ^ (row & 15)) << 3);
        *(f16x8*)(&Sl[ld]) = *(const f16x8*)(Shi + gsrc);
        hreg[it] = *(const f16x8*)(H + gsrc);
    }
    __syncthreads();

    f32x4 acc[2][8];
#pragma unroll
    for (int mi = 0; mi < 2; ++mi)
#pragma unroll
        for (int t = 0; t < 8; ++t) acc[mi][t] = (f32x4){0.f, 0.f, 0.f, 0.f};

    const _Float16* bw = Bsw + (size_t)(w * 8) * 8 * 512 + lane * 8;

    // S phases (gates r,z,i_n -> t=0..5); H global loads still in flight
#pragma unroll
    for (int p = 0; p < 4; ++p) {
        f16x8 a[2];
#pragma unroll
        for (int mi = 0; mi < 2; ++mi)
            a[mi] = *(const f16x8*)(&Sl[lidx(mi * 16 + l16, p * 32 + quad * 8)]);
#pragma unroll
        for (int t = 0; t < 6; ++t) {
            f16x8 b = *(const f16x8*)(bw + (size_t)(t * 8 + p) * 512);
#pragma unroll
            for (int mi = 0; mi < 2; ++mi)
                acc[mi][t] = __builtin_amdgcn_mfma_f32_16x16x32_f16(a[mi], b, acc[mi][t], 0, 0, 0);
        }
    }

    // now commit H regs -> LDS
#pragma unroll
    for (int it = 0; it < 2; ++it) {
        int c = it * 256 + tid;
        int row = c >> 4, kc = c & 15;
        int ld = row * 128 + ((kc ^ (row & 15)) << 3);
        *(f16x8*)(&Hh[ld]) = hreg[it];
    }
    __syncthreads();

    // H phases (gates r,z,h_n -> t={0,1,2,3,6,7})
#pragma unroll
    for (int p = 0; p < 4; ++p) {
        f16x8 a[2];
#pragma unroll
        for (int mi = 0; mi < 2; ++mi)
            a[mi] = *(const f16x8*)(&Hh[lidx(mi * 16 + l16, p * 32 + quad * 8)]);
#pragma unroll
        for (int tt = 0; tt < 6; ++tt) {
            int t = (tt < 4) ? tt : (tt + 2);
            f16x8 b = *(const f16x8*)(bw + (size_t)(t * 8 + p + 4) * 512);
#pragma unroll
            for (int mi = 0; mi < 2; ++mi)
                acc[mi][t] = __builtin_amdgcn_mfma_f32_16x16x32_f16(a[mi], b, acc[mi][t], 0, 0, 0);
        }
    }

    __syncthreads();   // all H-LDS A-reads done before epilogue overwrites Hh

    // epilogue: gates; in-place RMW on Hh (each li touched by exactly one thread)
#pragma unroll
    for (int ns = 0; ns < 2; ++ns) {
        int j = w * 32 + ns * 16 + l16;
        float br  = bih[j]       + bhh[j];
        float bz  = bih[j + 128] + bhh[j + 128];
        float bin = bih[j + 256];
        float bhn = bhh[j + 256];
#pragma unroll
        for (int mi = 0; mi < 2; ++mi) {
#pragma unroll
            for (int reg = 0; reg < 4; ++reg) {
                int row = mi * 16 + quad * 4 + reg;
                int li = lidx(row, j);
                float hold = (float)Hh[li];
                float r = sigm(acc[mi][0 + ns][reg] + br);
                float z = sigm(acc[mi][2 + ns][reg] + bz);
                float n = tanhfast(acc[mi][4 + ns][reg] + bin + r * (acc[mi][6 + ns][reg] + bhn));
                Hh[li] = (_Float16)((1.f - z) * n + z * hold);
            }
        }
    }
    __syncthreads();

#pragma unroll
    for (int it = 0; it < 2; ++it) {
        int c = it * 256 + tid;
        int row = c >> 4, kc = c & 15;
        int grow = m0 + row;
        int ld = row * 128 + ((kc ^ (row & 15)) << 3);
        *(f16x8*)(H + (size_t)grow * HD + kc * 8) = *(const f16x8*)(&Hh[ld]);
    }
}

// ---------------- pooling + head ----------------
__global__ void k_ginit(int* __restrict__ gs, int* __restrict__ ge) {
    int g = threadIdx.x;
    if (g < NG) { gs[g] = 0; ge[g] = 0; }
}

__global__ void k_bounds(const int* __restrict__ batch, int* __restrict__ gs, int* __restrict__ ge) {
    int i = blockIdx.x * 256 + threadIdx.x;
    if (i >= NN) return;
    int b = batch[i];
    if (i == 0 || batch[i - 1] != b) gs[b] = i;
    if (i == NN - 1 || batch[i + 1] != b) ge[b] = i + 1;
}

// [R3 counters: old k_pool (128 thr, scalar 2B loads, serial ~195-node loop) was
//  68us, Occ 8%, HBM 2.4%, VALU 1.3% -- pure latency-bound. R4: 16 node-slots x
//  16 colgroups, f16x8 loads, 16 rows in flight, shfl slot-reduce (k_agg pattern).]
__global__ void __launch_bounds__(256) k_pool(const _Float16* __restrict__ H,
                       const int* __restrict__ gs, const int* __restrict__ ge,
                       const float* __restrict__ Wp, const float* __restrict__ bp,
                       float* __restrict__ out) {
    __shared__ float red[4][HD];
    __shared__ float red2[HD];
    int g = blockIdx.x, tid = threadIdx.x;
    int w = tid >> 6, lane = tid & 63;
    int slot = tid >> 4;        // 0..15 (global node-slot)
    int cg = tid & 15;          // col-group of 8
    int s = gs[g], e = ge[g];
    float a0 = 0.f, a1 = 0.f, a2 = 0.f, a3 = 0.f, a4 = 0.f, a5 = 0.f, a6 = 0.f, a7 = 0.f;
    for (int n = s + slot; n < e; n += 16) {
        f16x8 v = *(const f16x8*)(H + (size_t)n * HD + cg * 8);
        a0 += (float)v[0]; a1 += (float)v[1]; a2 += (float)v[2]; a3 += (float)v[3];
        a4 += (float)v[4]; a5 += (float)v[5]; a6 += (float)v[6]; a7 += (float)v[7];
    }
    // reduce the 4 slot-locals within each wave
    a0 += __shfl_down(a0, 32); a1 += __shfl_down(a1, 32);
    a2 += __shfl_down(a2, 32); a3 += __shfl_down(a3, 32);
    a4 += __shfl_down(a4, 32); a5 += __shfl_down(a5, 32);
    a6 += __shfl_down(a6, 32); a7 += __shfl_down(a7, 32);
    a0 += __shfl_down(a0, 16); a1 += __shfl_down(a1, 16);
    a2 += __shfl_down(a2, 16); a3 += __shfl_down(a3, 16);
    a4 += __shfl_down(a4, 16); a5 += __shfl_down(a5, 16);
    a6 += __shfl_down(a6, 16); a7 += __shfl_down(a7, 16);
    if (lane < 16) {
        red[w][cg * 8 + 0] = a0; red[w][cg * 8 + 1] = a1;
        red[w][cg * 8 + 2] = a2; red[w][cg * 8 + 3] = a3;
        red[w][cg * 8 + 4] = a4; red[w][cg * 8 + 5] = a5;
        red[w][cg * 8 + 6] = a6; red[w][cg * 8 + 7] = a7;
    }
    __syncthreads();
    if (tid < HD) {
        int cnt = e - s;
        float pooled = (red[0][tid] + red[1][tid] + red[2][tid] + red[3][tid])
                       / (float)(cnt > 0 ? cnt : 1);
        red2[tid] = fmaxf(pooled, 0.f) * Wp[tid];
    }
    __syncthreads();
    for (int off = 64; off > 0; off >>= 1) {
        if (tid < off) red2[tid] += red2[tid + off];
        __syncthreads();
    }
    if (tid == 0) out[g] = red2[0] + bp[0];
}

extern "C" void kernel_launch(void* const* d_in, const int* in_sizes, int n_in,
                              void* d_out, int out_size, void* d_ws, size_t ws_size,
                              hipStream_t stream) {
    const float* x   = (const float*)d_in[0];
    const int*   ei  = (const int*)d_in[1];
    const int*   bat = (const int*)d_in[2];
    const float* Win = (const float*)d_in[3];
    const float* Wmp = (const float*)d_in[4];
    const float* Wih = (const float*)d_in[5];
    const float* Whh = (const float*)d_in[6];
    const float* bih = (const float*)d_in[7];
    const float* bhh = (const float*)d_in[8];
    const float* Wp  = (const float*)d_in[9];
    const float* bp  = (const float*)d_in[10];
    float* out = (float*)d_out;

    const int* esrc = ei;
    const int* edst = ei + NE;

    char* w = (char*)d_ws;
    _Float16* H   = (_Float16*)w; w += (size_t)NN * HD * 2;
    _Float16* Shi = (_Float16*)w; w += (size_t)NN * HD * 2;
    _Float16* Bsw = (_Float16*)w; w += (size_t)NSTEP * 131072 * 2;
    _Float16* BihW = (_Float16*)w; w += 8192 * 2;
    _Float16* BilW = (_Float16*)w; w += 8192 * 2;
    int* indptr  = (int*)w;   w += 400128;
    int* cursor  = (int*)w;   w += 400128;   // counts during scan; bucket cursors after
    int* csr     = (int*)w;   w += (size_t)NE * 4;
    int* aux     = (int*)w;   w += 512;
    int* gs      = (int*)w;   w += NG * 4;
    int* ge      = (int*)w;   w += NG * 4;

    // pairs buffer aliases Shi (12.8MB; consumed by k_fill2 before first k_agg)
    int2* pairs = (int2*)Shi;
    int*  bcur  = cursor;    // counts no longer needed after scan3

    // CSR build: count -> scan -> bucket-bin -> dense per-bucket fill
    hipMemsetAsync(cursor, 0, (size_t)NN * 4, stream);
    k_count<<<NE / 256, 256, 0, stream>>>(edst, cursor);
    k_scan1<<<NBLK, 256, 0, stream>>>(cursor, indptr, aux);
    k_scan2<<<1, 128, 0, stream>>>(aux);
    k_scan3<<<NBLK, 256, 0, stream>>>(indptr, aux);
    k_bcinit<<<(NBUCK + 255) / 256, 256, 0, stream>>>(indptr, bcur);
    k_bin<<<BINBLK, 256, 0, stream>>>(esrc, edst, bcur, pairs);
    k_fill2<<<NBUCK, 256, 0, stream>>>(pairs, indptr, csr);

    // weight prep + input layer
    k_prepB<<<NSTEP * 512, 256, 0, stream>>>(Wmp, Wih, Whh, Bsw);
    k_prepWin<<<32, 256, 0, stream>>>(Win, BihW, BilW);
    k_input<<<(NN + 63) / 64, 256, 0, stream>>>(x, BihW, BilW, H);

    // 6 message-passing + fused GEMM/GRU steps (H updated in place)
    for (int st = 0; st < NSTEP; ++st) {
        k_agg<<<NN / 4, 256, 0, stream>>>(H, indptr, csr, Shi);
        k_ggemm<<<NN / 32, 256, 0, stream>>>(Shi, H,
                                             Bsw + (size_t)st * 131072,
                                             bih, bhh);
    }

    // pooling + head
    k_ginit<<<1, NG, 0, stream>>>(gs, ge);
    k_bounds<<<(NN + 255) / 256, 256, 0, stream>>>(bat, gs, ge);
    k_pool<<<NG, 256, 0, stream>>>(H, gs, ge, Wp, bp, out);
}

// Round 5
// 800.456 us; speedup vs baseline: 1.7130x; 1.0865x over previous
//
#include <hip/hip_runtime.h>

#define NN 100000
#define NE 1600000
#define NG 512
#define FIN 64
#define HD 128
#define NSTEP 6

// ---- bucketed CSR build geometry ----
#define BROWS 128               // dst nodes per bucket
#define NBUCK 782               // ceil(NN/BROWS)
#define BCAP 3072               // fixed pairs-capacity per bucket (mean 2048, sigma~45 -> 22-sigma headroom)
#define EPER 16                 // edges per thread in k_bin
#define BINBLK 391              // ceil(NE / (256*EPER))

typedef _Float16 f16x8 __attribute__((ext_vector_type(8)));
typedef _Float16 f16x4 __attribute__((ext_vector_type(4)));
typedef float    f32x4 __attribute__((ext_vector_type(4)));

__device__ __forceinline__ float sigm(float x) { return 1.f / (1.f + __expf(-x)); }
__device__ __forceinline__ float tanhfast(float x) { return 2.f / (1.f + __expf(-2.f * x)) - 1.f; }

// LDS tile index with XOR swizzle (128-col tiles, 16B chunks)
__device__ __forceinline__ int lidx(int r, int col) {
    return r * 128 + ((((col >> 3) ^ (r & 15)) << 3) | (col & 7));
}

// ---------------- CSR build ----------------
// [R0: direct-scatter fill = 105MB write-amp, 126us. R1: bucketed 2-phase = ~25us. KEEP.
//  R4 counters: k_count (1.6M random per-NODE atomics) = 66us, WRITE_SIZE 49.9MB for a
//  400KB array (64B line per 4B RMW). R5: k_count + scan1/2/3 ELIMINATED -- buckets get
//  fixed BCAP windows in pairs, k_bin reserves from zero-based cursors, bucket counts
//  come out of k_bin for free, 782-entry scan gives bases, and k_fill2 rebuilds per-node
//  indptr from an in-LDS count+scan of its (L2-hot) bucket window.]

// phase 1: bin (src,dst) pairs into fixed-capacity per-bucket windows
__global__ void __launch_bounds__(256) k_bin(const int* __restrict__ src, const int* __restrict__ dst,
                                             int* __restrict__ bcur, int2* __restrict__ pairs) {
    __shared__ int hist[NBUCK];
    __shared__ int base[NBUCK];
    int tid = threadIdx.x;
    for (int i = tid; i < NBUCK; i += 256) hist[i] = 0;
    __syncthreads();
    int e0 = blockIdx.x * (256 * EPER) + tid;
    int s[EPER], d[EPER], rk[EPER];
#pragma unroll
    for (int k = 0; k < EPER; ++k) {
        int e = e0 + k * 256;
        if (e < NE) {
            s[k] = src[e];
            d[k] = dst[e];
            rk[k] = atomicAdd(&hist[d[k] >> 7], 1);   // LDS atomic: local rank within (block,bucket)
        }
    }
    __syncthreads();
    for (int i = tid; i < NBUCK; i += 256) {
        int c = hist[i];
        base[i] = c ? atomicAdd(&bcur[i], c) : 0;     // one global atomic per (block,bucket); bcur starts at 0
    }
    __syncthreads();
#pragma unroll
    for (int k = 0; k < EPER; ++k) {
        int e = e0 + k * 256;
        if (e < NE) {
            int b = d[k] >> 7;
            pairs[(size_t)b * BCAP + base[b] + rk[k]] = make_int2(s[k], d[k]);
        }
    }
}

// scan 782 bucket counts -> bucket bases (1 block, 1024 threads)
__global__ void k_bscan(const int* __restrict__ bcnt, int* __restrict__ bbase) {
    __shared__ int sh[1024];
    int tid = threadIdx.x;
    int v = (tid < NBUCK) ? bcnt[tid] : 0;
    sh[tid] = v;
    __syncthreads();
    for (int off = 1; off < 1024; off <<= 1) {
        int t = (tid >= off) ? sh[tid - off] : 0;
        __syncthreads();
        sh[tid] += t;
        __syncthreads();
    }
    if (tid < NBUCK) bbase[tid] = sh[tid] - v;
    if (tid == NBUCK - 1) bbase[NBUCK] = sh[tid];    // = NE
}

// phase 2: one block per bucket; rebuild per-node indptr + dense csr window
__global__ void __launch_bounds__(256) k_fill2(const int2* __restrict__ pairs,
                                               const int* __restrict__ bcnt,
                                               const int* __restrict__ bbase,
                                               int* __restrict__ indptr,
                                               int* __restrict__ csr) {
    __shared__ int cnt[BROWS];
    __shared__ int ip[BROWS];
    __shared__ int sc[BROWS];
    int b = blockIdx.x, tid = threadIdx.x;
    int n0 = b * BROWS;
    if (tid < BROWS) cnt[tid] = 0;
    __syncthreads();
    int ec = bcnt[b];
    const int2* pw = pairs + (size_t)b * BCAP;
    // pass A: per-node counts within bucket
    for (int i = tid; i < ec; i += 256)
        atomicAdd(&cnt[pw[i].y & (BROWS - 1)], 1);
    __syncthreads();
    // exclusive scan of 128 counts
    if (tid < BROWS) sc[tid] = cnt[tid];
    __syncthreads();
    for (int off = 1; off < BROWS; off <<= 1) {
        int t = (tid < BROWS && tid >= off) ? sc[tid - off] : 0;
        __syncthreads();
        if (tid < BROWS) sc[tid] += t;
        __syncthreads();
    }
    int base = bbase[b];
    if (tid < BROWS) {
        int v = base + sc[tid] - cnt[tid];
        ip[tid] = v;
        int n = n0 + tid;
        if (n < NN) indptr[n] = v;
        cnt[tid] = 0;
    }
    if (b == NBUCK - 1 && tid == 0) indptr[NN] = NE;
    __syncthreads();
    // pass B: place edges (bucket window is L2-hot from pass A)
    for (int i = tid; i < ec; i += 256) {
        int2 p = pw[i];
        int li = p.y & (BROWS - 1);
        int r = atomicAdd(&cnt[li], 1);
        csr[ip[li] + r] = p.x;
    }
}

// ---------------- B prep (GRU weights), swizzled to MFMA fragment order ----------------
// Logical Bcat[c][k]: c=0..511 (g=c>>7: 0=r,1=z,2=i_n,3=h_n; j=c&127), k=0..255.
//   k<128:  g!=3 ? Weff[s][k][jj] : 0    (Weff = Wmp[s] @ Wih^T)
//   k>=128: g!=2 ? Whh[jj][k-128] : 0
__global__ void k_prepB(const float* __restrict__ Wmp, const float* __restrict__ Wih,
                        const float* __restrict__ Whh, _Float16* __restrict__ Bsw) {
    __shared__ float wih[HD];
    int b = blockIdx.x;          // s*512 + c
    int s = b >> 9;
    int c = b & 511;
    int g = c >> 7;
    int j = c & 127;
    int jj = (g < 2) ? c : (j + 256);
    int k = threadIdx.x;         // 0..255
    if (k < HD) wih[k] = Wih[(size_t)jj * HD + k];
    __syncthreads();
    float val = 0.f;
    if (k < 128) {
        if (g != 3) {
            const float* wm = Wmp + ((size_t)s * HD + k) * HD;
            float acc = 0.f;
#pragma unroll 8
            for (int t = 0; t < HD; ++t) acc += wm[t] * wih[t];
            val = acc;
        }
    } else {
        if (g != 2) val = Whh[(size_t)jj * HD + (k - 128)];
    }
    int l16 = c & 15, sub = (c >> 4) & 1, w = (c >> 5) & 3;
    int t = g * 2 + sub;
    int p = k >> 5, quad = (k >> 3) & 3, je = k & 7;
    size_t idx = (size_t)s * 131072 + ((size_t)((w * 8 + t) * 8 + p) * 64 + quad * 16 + l16) * 8 + je;
    Bsw[idx] = (_Float16)val;
}

// ---------------- W_in prep: fragment-order hi/lo fp16 ----------------
__global__ void k_prepWin(const float* __restrict__ Win,
                          _Float16* __restrict__ BihW, _Float16* __restrict__ BilW) {
    int gid = blockIdx.x * 256 + threadIdx.x;   // 0..8191
    int jj = gid & 7;
    int lane = (gid >> 3) & 63;
    int p = (gid >> 9) & 1;
    int t = (gid >> 10) & 7;
    int k = p * 32 + (lane >> 4) * 8 + jj;
    int col = t * 16 + (lane & 15);
    float val = Win[(size_t)k * HD + col];
    _Float16 hi = (_Float16)val;
    BihW[gid] = hi;
    BilW[gid] = (_Float16)(val - (float)hi);
}

// ---------------- input layer (MFMA): h = tanh(x @ W_in), fp16 out ----------------
__global__ void __launch_bounds__(256) k_input(const float* __restrict__ x,
                                               const _Float16* __restrict__ BihW,
                                               const _Float16* __restrict__ BilW,
                                               _Float16* __restrict__ H) {
    __shared__ _Float16 Xh[64 * 64];
    __shared__ _Float16 Xl[64 * 64];
    __shared__ _Float16 Oh[64 * 128];
    int tid = threadIdx.x;
    int w = tid >> 6, lane = tid & 63;
    int quad = lane >> 4, l16 = lane & 15;
    int m0 = blockIdx.x * 64;

#pragma unroll
    for (int it = 0; it < 4; ++it) {
        int c = it * 256 + tid;          // 1024 chunks of 4 floats
        int row = c >> 4, cc = c & 15;
        int grow = m0 + row; if (grow >= NN) grow = NN - 1;
        float4 v = ((const float4*)(x + (size_t)grow * FIN))[cc];
        f16x4 vh, vl;
        vh[0] = (_Float16)v.x; vl[0] = (_Float16)(v.x - (float)vh[0]);
        vh[1] = (_Float16)v.y; vl[1] = (_Float16)(v.y - (float)vh[1]);
        vh[2] = (_Float16)v.z; vl[2] = (_Float16)(v.z - (float)vh[2]);
        vh[3] = (_Float16)v.w; vl[3] = (_Float16)(v.w - (float)vh[3]);
        int ld = row * 64 + ((((cc >> 1) ^ (row & 7)) << 3)) + (cc & 1) * 4;
        *(f16x4*)(&Xh[ld]) = vh;
        *(f16x4*)(&Xl[ld]) = vl;
    }
    __syncthreads();

    f32x4 acc[4][2];
#pragma unroll
    for (int mi = 0; mi < 4; ++mi) { acc[mi][0] = (f32x4){0,0,0,0}; acc[mi][1] = (f32x4){0,0,0,0}; }

#pragma unroll
    for (int p = 0; p < 2; ++p) {
        int ch = p * 4 + quad;
        f16x8 ah[4], al[4];
#pragma unroll
        for (int mi = 0; mi < 4; ++mi) {
            int r = mi * 16 + l16;
            int li = r * 64 + ((ch ^ (r & 7)) << 3);
            ah[mi] = *(const f16x8*)(&Xh[li]);
            al[mi] = *(const f16x8*)(&Xl[li]);
        }
#pragma unroll
        for (int t2 = 0; t2 < 2; ++t2) {
            int t = w * 2 + t2;
            f16x8 bh = *(const f16x8*)(BihW + ((size_t)(t * 2 + p) * 64 + lane) * 8);
            f16x8 blv = *(const f16x8*)(BilW + ((size_t)(t * 2 + p) * 64 + lane) * 8);
#pragma unroll
            for (int mi = 0; mi < 4; ++mi) {
                acc[mi][t2] = __builtin_amdgcn_mfma_f32_16x16x32_f16(ah[mi], bh, acc[mi][t2], 0, 0, 0);
                acc[mi][t2] = __builtin_amdgcn_mfma_f32_16x16x32_f16(ah[mi], blv, acc[mi][t2], 0, 0, 0);
                acc[mi][t2] = __builtin_amdgcn_mfma_f32_16x16x32_f16(al[mi], bh, acc[mi][t2], 0, 0, 0);
            }
        }
    }

#pragma unroll
    for (int t2 = 0; t2 < 2; ++t2) {
        int j = (w * 2 + t2) * 16 + l16;
#pragma unroll
        for (int mi = 0; mi < 4; ++mi) {
#pragma unroll
            for (int reg = 0; reg < 4; ++reg) {
                int row = mi * 16 + quad * 4 + reg;
                Oh[lidx(row, j)] = (_Float16)tanhfast(acc[mi][t2][reg]);
            }
        }
    }
    __syncthreads();
#pragma unroll
    for (int it = 0; it < 4; ++it) {
        int c = it * 256 + tid;
        int row = c >> 4, kc = c & 15;
        int grow = m0 + row;
        if (grow < NN) {
            int ld = row * 128 + ((kc ^ (row & 15)) << 3);
            *(f16x8*)(H + (size_t)grow * HD + kc * 8) = *(const f16x8*)(&Oh[ld]);
        }
    }
}

// ---------------- aggregation: S[v] = sum_{in-edges} H[src], fp16 out ----------------
// [R2 post-mortem: fusing this into the GEMM (k_step) REGRESSED 161->188us/step.
//  The gather is latency-bound and needs max TLP: 25000 blocks/100K waves here vs
//  1563 blocks/8 waves-per-CU fused. KEEP SPLIT.]
__global__ void k_agg(const _Float16* __restrict__ H, const int* __restrict__ indptr,
                      const int* __restrict__ csr, _Float16* __restrict__ Shi) {
    int v = blockIdx.x * 4 + (threadIdx.x >> 6);
    int lane = threadIdx.x & 63;
    int slot = lane >> 4;
    int cg = lane & 15;
    const _Float16* hp = H + cg * 8;
    int s = indptr[v], e = indptr[v + 1];
    float a0 = 0.f, a1 = 0.f, a2 = 0.f, a3 = 0.f, a4 = 0.f, a5 = 0.f, a6 = 0.f, a7 = 0.f;
    int i = s + slot;
    for (; i + 12 < e; i += 16) {
        int u0 = csr[i], u1 = csr[i + 4], u2 = csr[i + 8], u3 = csr[i + 12];
        f16x8 t0 = *(const f16x8*)(hp + (size_t)u0 * HD);
        f16x8 t1 = *(const f16x8*)(hp + (size_t)u1 * HD);
        f16x8 t2 = *(const f16x8*)(hp + (size_t)u2 * HD);
        f16x8 t3 = *(const f16x8*)(hp + (size_t)u3 * HD);
        a0 += (float)t0[0] + (float)t1[0] + (float)t2[0] + (float)t3[0];
        a1 += (float)t0[1] + (float)t1[1] + (float)t2[1] + (float)t3[1];
        a2 += (float)t0[2] + (float)t1[2] + (float)t2[2] + (float)t3[2];
        a3 += (float)t0[3] + (float)t1[3] + (float)t2[3] + (float)t3[3];
        a4 += (float)t0[4] + (float)t1[4] + (float)t2[4] + (float)t3[4];
        a5 += (float)t0[5] + (float)t1[5] + (float)t2[5] + (float)t3[5];
        a6 += (float)t0[6] + (float)t1[6] + (float)t2[6] + (float)t3[6];
        a7 += (float)t0[7] + (float)t1[7] + (float)t2[7] + (float)t3[7];
    }
    for (; i < e; i += 4) {
        int u0 = csr[i];
        f16x8 t0 = *(const f16x8*)(hp + (size_t)u0 * HD);
        a0 += (float)t0[0]; a1 += (float)t0[1]; a2 += (float)t0[2]; a3 += (float)t0[3];
        a4 += (float)t0[4]; a5 += (float)t0[5]; a6 += (float)t0[6]; a7 += (float)t0[7];
    }
    a0 += __shfl_down(a0, 32); a1 += __shfl_down(a1, 32);
    a2 += __shfl_down(a2, 32); a3 += __shfl_down(a3, 32);
    a4 += __shfl_down(a4, 32); a5 += __shfl_down(a5, 32);
    a6 += __shfl_down(a6, 32); a7 += __shfl_down(a7, 32);
    a0 += __shfl_down(a0, 16); a1 += __shfl_down(a1, 16);
    a2 += __shfl_down(a2, 16); a3 += __shfl_down(a3, 16);
    a4 += __shfl_down(a4, 16); a5 += __shfl_down(a5, 16);
    a6 += __shfl_down(a6, 16); a7 += __shfl_down(a7, 16);
    if (lane < 16) {
        f16x8 o;
        o[0] = (_Float16)a0; o[1] = (_Float16)a1; o[2] = (_Float16)a2; o[3] = (_Float16)a3;
        o[4] = (_Float16)a4; o[5] = (_Float16)a5; o[6] = (_Float16)a6; o[7] = (_Float16)a7;
        *(f16x8*)(Shi + (size_t)v * HD + cg * 8) = o;
    }
}

// ---------------- fused MFMA GEMM + GRU gates (H fp16, in place) ----------------
// [R2: 64-row tile = 212 regs -> 2 blocks/CU (Occ 24%), 81us. R3: 32-row tile ->
//  acc[2][8], 3 waves/SIMD, H staged via regs under S-phase MFMAs -> out of top-5
//  (<66us). KEEP.]
__global__ void __launch_bounds__(256, 3) k_ggemm(
        const _Float16* __restrict__ Shi, _Float16* __restrict__ H,
        const _Float16* __restrict__ Bsw,
        const float* __restrict__ bih, const float* __restrict__ bhh) {
    __shared__ _Float16 Sl[32 * 128];
    __shared__ _Float16 Hh[32 * 128];
    int tid = threadIdx.x;
    int w = tid >> 6, lane = tid & 63;
    int quad = lane >> 4, l16 = lane & 15;
    int m0 = blockIdx.x * 32;

    // stage: Sl -> LDS now; H -> regs (LDS write deferred under S-phase MFMAs)
    f16x8 hreg[2];
#pragma unroll
    for (int it = 0; it < 2; ++it) {
        int c = it * 256 + tid;
        int row = c >> 4, kc = c & 15;
        int grow = m0 + row;
        size_t gsrc = (size_t)grow * HD + kc * 8;
        int ld = row * 128 + ((kc ^ (row & 15)) << 3);
        *(f16x8*)(&Sl[ld]) = *(const f16x8*)(Shi + gsrc);
        hreg[it] = *(const f16x8*)(H + gsrc);
    }
    __syncthreads();

    f32x4 acc[2][8];
#pragma unroll
    for (int mi = 0; mi < 2; ++mi)
#pragma unroll
        for (int t = 0; t < 8; ++t) acc[mi][t] = (f32x4){0.f, 0.f, 0.f, 0.f};

    const _Float16* bw = Bsw + (size_t)(w * 8) * 8 * 512 + lane * 8;

    // S phases (gates r,z,i_n -> t=0..5); H global loads still in flight
#pragma unroll
    for (int p = 0; p < 4; ++p) {
        f16x8 a[2];
#pragma unroll
        for (int mi = 0; mi < 2; ++mi)
            a[mi] = *(const f16x8*)(&Sl[lidx(mi * 16 + l16, p * 32 + quad * 8)]);
#pragma unroll
        for (int t = 0; t < 6; ++t) {
            f16x8 b = *(const f16x8*)(bw + (size_t)(t * 8 + p) * 512);
#pragma unroll
            for (int mi = 0; mi < 2; ++mi)
                acc[mi][t] = __builtin_amdgcn_mfma_f32_16x16x32_f16(a[mi], b, acc[mi][t], 0, 0, 0);
        }
    }

    // now commit H regs -> LDS
#pragma unroll
    for (int it = 0; it < 2; ++it) {
        int c = it * 256 + tid;
        int row = c >> 4, kc = c & 15;
        int ld = row * 128 + ((kc ^ (row & 15)) << 3);
        *(f16x8*)(&Hh[ld]) = hreg[it];
    }
    __syncthreads();

    // H phases (gates r,z,h_n -> t={0,1,2,3,6,7})
#pragma unroll
    for (int p = 0; p < 4; ++p) {
        f16x8 a[2];
#pragma unroll
        for (int mi = 0; mi < 2; ++mi)
            a[mi] = *(const f16x8*)(&Hh[lidx(mi * 16 + l16, p * 32 + quad * 8)]);
#pragma unroll
        for (int tt = 0; tt < 6; ++tt) {
            int t = (tt < 4) ? tt : (tt + 2);
            f16x8 b = *(const f16x8*)(bw + (size_t)(t * 8 + p + 4) * 512);
#pragma unroll
            for (int mi = 0; mi < 2; ++mi)
                acc[mi][t] = __builtin_amdgcn_mfma_f32_16x16x32_f16(a[mi], b, acc[mi][t], 0, 0, 0);
        }
    }

    __syncthreads();   // all H-LDS A-reads done before epilogue overwrites Hh

    // epilogue: gates; in-place RMW on Hh (each li touched by exactly one thread)
#pragma unroll
    for (int ns = 0; ns < 2; ++ns) {
        int j = w * 32 + ns * 16 + l16;
        float br  = bih[j]       + bhh[j];
        float bz  = bih[j + 128] + bhh[j + 128];
        float bin = bih[j + 256];
        float bhn = bhh[j + 256];
#pragma unroll
        for (int mi = 0; mi < 2; ++mi) {
#pragma unroll
            for (int reg = 0; reg < 4; ++reg) {
                int row = mi * 16 + quad * 4 + reg;
                int li = lidx(row, j);
                float hold = (float)Hh[li];
                float r = sigm(acc[mi][0 + ns][reg] + br);
                float z = sigm(acc[mi][2 + ns][reg] + bz);
                float n = tanhfast(acc[mi][4 + ns][reg] + bin + r * (acc[mi][6 + ns][reg] + bhn));
                Hh[li] = (_Float16)((1.f - z) * n + z * hold);
            }
        }
    }
    __syncthreads();

#pragma unroll
    for (int it = 0; it < 2; ++it) {
        int c = it * 256 + tid;
        int row = c >> 4, kc = c & 15;
        int grow = m0 + row;
        int ld = row * 128 + ((kc ^ (row & 15)) << 3);
        *(f16x8*)(H + (size_t)grow * HD + kc * 8) = *(const f16x8*)(&Hh[ld]);
    }
}

// ---------------- pooling + head ----------------
__global__ void k_ginit(int* __restrict__ gs, int* __restrict__ ge) {
    int g = threadIdx.x;
    if (g < NG) { gs[g] = 0; ge[g] = 0; }
}

__global__ void k_bounds(const int* __restrict__ batch, int* __restrict__ gs, int* __restrict__ ge) {
    int i = blockIdx.x * 256 + threadIdx.x;
    if (i >= NN) return;
    int b = batch[i];
    if (i == 0 || batch[i - 1] != b) gs[b] = i;
    if (i == NN - 1 || batch[i + 1] != b) ge[b] = i + 1;
}

// [R3: old k_pool (scalar 2B loads, serial loop) was 68us, Occ 8%. R4: slot x colgroup
//  f16x8 restructure -> out of top-5. KEEP.]
__global__ void __launch_bounds__(256) k_pool(const _Float16* __restrict__ H,
                       const int* __restrict__ gs, const int* __restrict__ ge,
                       const float* __restrict__ Wp, const float* __restrict__ bp,
                       float* __restrict__ out) {
    __shared__ float red[4][HD];
    __shared__ float red2[HD];
    int g = blockIdx.x, tid = threadIdx.x;
    int w = tid >> 6, lane = tid & 63;
    int slot = tid >> 4;        // 0..15 (global node-slot)
    int cg = tid & 15;          // col-group of 8
    int s = gs[g], e = ge[g];
    float a0 = 0.f, a1 = 0.f, a2 = 0.f, a3 = 0.f, a4 = 0.f, a5 = 0.f, a6 = 0.f, a7 = 0.f;
    for (int n = s + slot; n < e; n += 16) {
        f16x8 v = *(const f16x8*)(H + (size_t)n * HD + cg * 8);
        a0 += (float)v[0]; a1 += (float)v[1]; a2 += (float)v[2]; a3 += (float)v[3];
        a4 += (float)v[4]; a5 += (float)v[5]; a6 += (float)v[6]; a7 += (float)v[7];
    }
    // reduce the 4 slot-locals within each wave
    a0 += __shfl_down(a0, 32); a1 += __shfl_down(a1, 32);
    a2 += __shfl_down(a2, 32); a3 += __shfl_down(a3, 32);
    a4 += __shfl_down(a4, 32); a5 += __shfl_down(a5, 32);
    a6 += __shfl_down(a6, 32); a7 += __shfl_down(a7, 32);
    a0 += __shfl_down(a0, 16); a1 += __shfl_down(a1, 16);
    a2 += __shfl_down(a2, 16); a3 += __shfl_down(a3, 16);
    a4 += __shfl_down(a4, 16); a5 += __shfl_down(a5, 16);
    a6 += __shfl_down(a6, 16); a7 += __shfl_down(a7, 16);
    if (lane < 16) {
        red[w][cg * 8 + 0] = a0; red[w][cg * 8 + 1] = a1;
        red[w][cg * 8 + 2] = a2; red[w][cg * 8 + 3] = a3;
        red[w][cg * 8 + 4] = a4; red[w][cg * 8 + 5] = a5;
        red[w][cg * 8 + 6] = a6; red[w][cg * 8 + 7] = a7;
    }
    __syncthreads();
    if (tid < HD) {
        int cnt = e - s;
        float pooled = (red[0][tid] + red[1][tid] + red[2][tid] + red[3][tid])
                       / (float)(cnt > 0 ? cnt : 1);
        red2[tid] = fmaxf(pooled, 0.f) * Wp[tid];
    }
    __syncthreads();
    for (int off = 64; off > 0; off >>= 1) {
        if (tid < off) red2[tid] += red2[tid + off];
        __syncthreads();
    }
    if (tid == 0) out[g] = red2[0] + bp[0];
}

extern "C" void kernel_launch(void* const* d_in, const int* in_sizes, int n_in,
                              void* d_out, int out_size, void* d_ws, size_t ws_size,
                              hipStream_t stream) {
    const float* x   = (const float*)d_in[0];
    const int*   ei  = (const int*)d_in[1];
    const int*   bat = (const int*)d_in[2];
    const float* Win = (const float*)d_in[3];
    const float* Wmp = (const float*)d_in[4];
    const float* Wih = (const float*)d_in[5];
    const float* Whh = (const float*)d_in[6];
    const float* bih = (const float*)d_in[7];
    const float* bhh = (const float*)d_in[8];
    const float* Wp  = (const float*)d_in[9];
    const float* bp  = (const float*)d_in[10];
    float* out = (float*)d_out;

    const int* esrc = ei;
    const int* edst = ei + NE;

    char* w = (char*)d_ws;
    _Float16* H   = (_Float16*)w; w += (size_t)NN * HD * 2;
    _Float16* Shi = (_Float16*)w; w += (size_t)NN * HD * 2;
    _Float16* Bsw = (_Float16*)w; w += (size_t)NSTEP * 131072 * 2;
    _Float16* BihW = (_Float16*)w; w += 8192 * 2;
    _Float16* BilW = (_Float16*)w; w += 8192 * 2;
    int* indptr  = (int*)w;   w += 400128;
    int* scratch = (int*)w;   w += 400128;   // bcur (782) @ +0; bbase (783) @ +1024
    int* csr     = (int*)w;   w += (size_t)NE * 4;
    int* gs      = (int*)w;   w += NG * 4;
    int* ge      = (int*)w;   w += NG * 4;

    int*  bcur  = scratch;
    int*  bbase = scratch + 1024;
    // pairs buffer aliases Shi (19.2MB < 25.6MB; consumed by k_fill2 before first k_agg)
    int2* pairs = (int2*)Shi;

    // CSR build: bin into fixed-cap bucket windows -> 782-scan -> per-bucket indptr+fill
    hipMemsetAsync(bcur, 0, NBUCK * 4, stream);
    k_bin<<<BINBLK, 256, 0, stream>>>(esrc, edst, bcur, pairs);
    k_bscan<<<1, 1024, 0, stream>>>(bcur, bbase);
    k_fill2<<<NBUCK, 256, 0, stream>>>(pairs, bcur, bbase, indptr, csr);

    // weight prep + input layer
    k_prepB<<<NSTEP * 512, 256, 0, stream>>>(Wmp, Wih, Whh, Bsw);
    k_prepWin<<<32, 256, 0, stream>>>(Win, BihW, BilW);
    k_input<<<(NN + 63) / 64, 256, 0, stream>>>(x, BihW, BilW, H);

    // 6 message-passing + fused GEMM/GRU steps (H updated in place)
    for (int st = 0; st < NSTEP; ++st) {
        k_agg<<<NN / 4, 256, 0, stream>>>(H, indptr, csr, Shi);
        k_ggemm<<<NN / 32, 256, 0, stream>>>(Shi, H,
                                             Bsw + (size_t)st * 131072,
                                             bih, bhh);
    }

    // pooling + head
    k_ginit<<<1, NG, 0, stream>>>(gs, ge);
    k_bounds<<<(NN + 255) / 256, 256, 0, stream>>>(bat, gs, ge);
    k_pool<<<NG, 256, 0, stream>>>(H, gs, ge, Wp, bp, out);
}